// Round 12
// baseline (494.121 us; speedup 1.0000x reference)
//
#include <hip/hip_runtime.h>
#include <hip/hip_bf16.h>
#include <math.h>

#define N_NODES 12288
#define N_EDGES 196608
#define EP_EDGES (N_EDGES + N_NODES)   // 208896 edges incl. self loops
#define HEADS 4
#define HID 256
#define FDIM 1024                      // HEADS*HID
#define EMB 16
#define NEG_SLOPE 0.2f

typedef __attribute__((ext_vector_type(8))) short short8;
typedef __attribute__((ext_vector_type(4))) float f32x4;
typedef __attribute__((ext_vector_type(2))) float f32x2;

// bf16 helpers (RNE)
__device__ __forceinline__ unsigned short f2bf(float f) {
  unsigned int u = __float_as_uint(f);
  u = (u + 0x7FFFu + ((u >> 16) & 1u)) >> 16;
  return (unsigned short)u;
}
__device__ __forceinline__ float bf2f(unsigned short h) {
  return __uint_as_float(((unsigned int)h) << 16);
}

// ---------------- K1: hist ∥ x->bf16 ∥ W1t ∥ W2t ∥ wa ∥ W3t -------------------------
__device__ __forceinline__ void t_tile_hi(const float* __restrict__ W,
                                          unsigned short* __restrict__ Th,
                                          int K, int N, int k0, int n0,
                                          int t, float (*tile)[33]) {
  int rr = t >> 3, cc = (t & 7) * 4;
  float4 v = *reinterpret_cast<const float4*>(&W[(size_t)(k0 + rr) * N + n0 + cc]);
  tile[rr][cc + 0] = v.x; tile[rr][cc + 1] = v.y; tile[rr][cc + 2] = v.z; tile[rr][cc + 3] = v.w;
  __syncthreads();
  ushort4 h;
  h.x = f2bf(tile[cc + 0][rr]);
  h.y = f2bf(tile[cc + 1][rr]);
  h.z = f2bf(tile[cc + 2][rr]);
  h.w = f2bf(tile[cc + 3][rr]);
  *reinterpret_cast<ushort4*>(&Th[(size_t)(n0 + rr) * K + k0 + cc]) = h;
}

#define HIST_BLKS (EP_EDGES / 256)     // 816
__global__ __launch_bounds__(256) void k_hist_prep(const int* __restrict__ ei,
                                                   int* __restrict__ cnt,
                                                   const float* __restrict__ x,
                                                   unsigned short* __restrict__ xbf,
                                                   const float* __restrict__ W1,
                                                   unsigned short* __restrict__ w1tHi,
                                                   const float* __restrict__ W2,
                                                   unsigned short* __restrict__ w2tHi,
                                                   const float* __restrict__ as1,
                                                   const float* __restrict__ ad1,
                                                   float* __restrict__ wa,
                                                   const float* __restrict__ W3,
                                                   unsigned short* __restrict__ w3t) {
  __shared__ float tile[32][33];
  int b = blockIdx.x, t = threadIdx.x;
  if (b < HIST_BLKS) {
    int i = b * 256 + t;
    if (i < EP_EDGES) {
      int d = (i < N_EDGES) ? ei[N_EDGES + i] : (i - N_EDGES);
      atomicAdd(&cnt[d], 1);
    }
  } else if (b < HIST_BLKS + 1536) {               // x convert
    int i = (b - HIST_BLKS) * 256 + t;
    float4 v = *reinterpret_cast<const float4*>(&x[(size_t)i * 4]);
    ushort4 h;
    h.x = f2bf(v.x); h.y = f2bf(v.y); h.z = f2bf(v.z); h.w = f2bf(v.w);
    *reinterpret_cast<ushort4*>(&xbf[(size_t)i * 4]) = h;
  } else if (b < HIST_BLKS + 1536 + 128) {         // W1 [128,1024] -> [1024,128] bf16
    int tt = b - HIST_BLKS - 1536;
    t_tile_hi(W1, w1tHi, 128, FDIM, (tt >> 5) * 32, (tt & 31) * 32, t, tile);
  } else if (b < HIST_BLKS + 1536 + 128 + 1024) {  // W2 [1024,1024] -> [1024,1024] bf16
    int tt = b - HIST_BLKS - 1536 - 128;
    t_tile_hi(W2, w2tHi, FDIM, FDIM, (tt >> 5) * 32, (tt & 31) * 32, t, tile);
  } else if (b == HIST_BLKS + 1536 + 128 + 1024) { // wa GEMV
    for (int idx = t; idx < 1024; idx += 256) {
      int sd = idx >> 9, h = (idx >> 7) & 3, k = idx & 127;
      const float* av = sd ? ad1 : as1;
      float acc = 0.f;
      for (int f = 0; f < 256; ++f)
        acc = fmaf(W1[(size_t)k * FDIM + h * 256 + f], av[h * 256 + f], acc);
      wa[idx] = acc;
    }
  } else {                                         // W3 [1024,16] -> w3t [16,1024] bf16
    for (int idx = t; idx < 16384; idx += 256) {
      int c = idx >> 10, k = idx & 1023;
      w3t[idx] = f2bf(W3[(size_t)k * 16 + c]);
    }
  }
}

// ---------------- K2: scan1 (blocks 0-11) ∥ alpha_x (blocks 12-59), 1024 thr --------
__global__ __launch_bounds__(1024) void k_scan_alpha(const int* __restrict__ cnt,
                                                     int* __restrict__ row_ptr,
                                                     int* __restrict__ bsum,
                                                     const float* __restrict__ x,
                                                     const float* __restrict__ wa,
                                                     float* __restrict__ asrc,
                                                     float* __restrict__ adst) {
  __shared__ int sd[1024];
  int tid = threadIdx.x;
  if (blockIdx.x < 12) {                           // exclusive scan of cnt
    int gid = blockIdx.x * 1024 + tid;
    int v = cnt[gid];
    sd[tid] = v;
    __syncthreads();
    for (int d = 1; d < 1024; d <<= 1) {
      int t2 = (tid >= d) ? sd[tid - d] : 0;
      __syncthreads();
      sd[tid] += t2;
      __syncthreads();
    }
    row_ptr[gid] = sd[tid] - v;
    if (tid == 1023) bsum[blockIdx.x] = sd[1023];
  } else {                                         // layer-1 alphas from x
    int id = (blockIdx.x - 12) * 1024 + tid;       // N*4
    int n = id >> 2, h = id & 3;
    const float* wsv = wa + h * 128;
    const float* wdv = wa + 512 + h * 128;
    const float* xr = x + (size_t)n * 128;
    float accs = 0.f, accd = 0.f;
#pragma unroll
    for (int k = 0; k < 128; k += 4) {
      float4 xv = *reinterpret_cast<const float4*>(&xr[k]);
      float4 s4 = *reinterpret_cast<const float4*>(&wsv[k]);
      float4 d4 = *reinterpret_cast<const float4*>(&wdv[k]);
      accs = fmaf(xv.x, s4.x, fmaf(xv.y, s4.y, fmaf(xv.z, s4.z, fmaf(xv.w, s4.w, accs))));
      accd = fmaf(xv.x, d4.x, fmaf(xv.y, d4.y, fmaf(xv.z, d4.z, fmaf(xv.w, d4.w, accd))));
    }
    asrc[n * 4 + h] = accs;
    adst[n * 4 + h] = accd;
  }
}

// ---------------- K3: add block offsets (scan2 inlined per-thread) ------------------
__global__ void k_scan23(int* __restrict__ row_ptr, const int* __restrict__ bsum) {
  int gid = blockIdx.x * 256 + threadIdx.x;
  int blk = gid >> 10;
  int boffv = 0;
  for (int j = 0; j < blk; ++j) boffv += bsum[j];
  row_ptr[gid] += boffv;
  if (gid == 0) {
    int tot = 0;
    for (int j = 0; j < 12; ++j) tot += bsum[j];
    row_ptr[N_NODES] = tot;
  }
}

__global__ void k_scatter(const int* __restrict__ ei, const int* __restrict__ row_ptr,
                          int* __restrict__ cur, int* __restrict__ csr_src) {
  int i = blockIdx.x * 256 + threadIdx.x;
  if (i >= EP_EDGES) return;
  int s, d;
  if (i < N_EDGES) { s = ei[i]; d = ei[N_EDGES + i]; }
  else             { s = i - N_EDGES; d = s; }
  int pos = row_ptr[d] + atomicAdd(&cur[d], 1);
  csr_src[pos] = s;
}

// ---------------- layer-1 aggregation: wave/node, 4 heads, two-pass softmax ----------
__global__ __launch_bounds__(256) void k_aggx(const unsigned short* __restrict__ xbf,
                                              const float* __restrict__ asrc,
                                              const float* __restrict__ adst,
                                              const int* __restrict__ row_ptr,
                                              const int* __restrict__ csr_src,
                                              unsigned short* __restrict__ outHi) {
  int node = (blockIdx.x * 256 + threadIdx.x) >> 6;
  int lane = threadIdx.x & 63;
  int beg = row_ptr[node], end = row_ptr[node + 1];
  float4 adn = *reinterpret_cast<const float4*>(&adst[node * 4]);
  // pass 1: true max per head (broadcast loads only)
  float m0 = -INFINITY, m1 = -INFINITY, m2 = -INFINITY, m3 = -INFINITY;
  for (int e = beg; e < end; ++e) {
    int sidx = csr_src[e];
    float4 av = *reinterpret_cast<const float4*>(&asrc[sidx * 4]);
    float a;
    a = av.x + adn.x; a = a > 0.f ? a : NEG_SLOPE * a; m0 = fmaxf(m0, a);
    a = av.y + adn.y; a = a > 0.f ? a : NEG_SLOPE * a; m1 = fmaxf(m1, a);
    a = av.z + adn.z; a = a > 0.f ? a : NEG_SLOPE * a; m2 = fmaxf(m2, a);
    a = av.w + adn.w; a = a > 0.f ? a : NEG_SLOPE * a; m3 = fmaxf(m3, a);
  }
  // pass 2: accumulate (no rescale chain — edges independent)
  float s0 = 0.f, s1 = 0.f, s2 = 0.f, s3 = 0.f;
  float a0x = 0.f, a0y = 0.f, a1x = 0.f, a1y = 0.f;
  float a2x = 0.f, a2y = 0.f, a3x = 0.f, a3y = 0.f;
  for (int e = beg; e < end; ++e) {
    int sidx = csr_src[e];
    float4 av = *reinterpret_cast<const float4*>(&asrc[sidx * 4]);
    ushort2 hu = *reinterpret_cast<const ushort2*>(&xbf[(size_t)sidx * 128 + lane * 2]);
    float hx = bf2f(hu.x), hy = bf2f(hu.y);
    float a, p;
    a = av.x + adn.x; a = a > 0.f ? a : NEG_SLOPE * a;
    p = __expf(a - m0); s0 += p; a0x = fmaf(p, hx, a0x); a0y = fmaf(p, hy, a0y);
    a = av.y + adn.y; a = a > 0.f ? a : NEG_SLOPE * a;
    p = __expf(a - m1); s1 += p; a1x = fmaf(p, hx, a1x); a1y = fmaf(p, hy, a1y);
    a = av.z + adn.z; a = a > 0.f ? a : NEG_SLOPE * a;
    p = __expf(a - m2); s2 += p; a2x = fmaf(p, hx, a2x); a2y = fmaf(p, hy, a2y);
    a = av.w + adn.w; a = a > 0.f ? a : NEG_SLOPE * a;
    p = __expf(a - m3); s3 += p; a3x = fmaf(p, hx, a3x); a3y = fmaf(p, hy, a3y);
  }
  size_t base = (size_t)node * 512 + lane * 2;
  ushort2 o;
  float inv;
  inv = 1.f / s0; o.x = f2bf(a0x * inv); o.y = f2bf(a0y * inv);
  *reinterpret_cast<ushort2*>(&outHi[base + 0 * 128]) = o;
  inv = 1.f / s1; o.x = f2bf(a1x * inv); o.y = f2bf(a1y * inv);
  *reinterpret_cast<ushort2*>(&outHi[base + 1 * 128]) = o;
  inv = 1.f / s2; o.x = f2bf(a2x * inv); o.y = f2bf(a2y * inv);
  *reinterpret_cast<ushort2*>(&outHi[base + 2 * 128]) = o;
  inv = 1.f / s3; o.x = f2bf(a3x * inv); o.y = f2bf(a3y * inv);
  *reinterpret_cast<ushort2*>(&outHi[base + 3 * 128]) = o;
}

// ---------------- bf16 MFMA GEMM: C[M,N] = A[M,K] @ B[N,K]^T, 128x128, BK=32 ---------
// MODE 1: head-sliced A (lda, aoff), bias+ELU, bf16 out.
// MODE 0: fp8 e4m3 out (shfl-transposed dword stores) + non-atomic alpha partials.
template <int MODE>
__global__ __launch_bounds__(256) void k_gemm(const unsigned short* __restrict__ A,
                                              const unsigned short* __restrict__ B,
                                              unsigned short* __restrict__ OutBf,
                                              unsigned int* __restrict__ Out8,
                                              const float* __restrict__ bias,
                                              const float* __restrict__ a_s,
                                              const float* __restrict__ a_d,
                                              float* __restrict__ asrcP,
                                              float* __restrict__ adstP,
                                              int M, int N, int K, int lda) {
  __shared__ unsigned short sA[128 * 32], sB[128 * 32];
  const int tid = threadIdx.x;
  const int lane = tid & 63, wv = tid >> 6;
  const int row0 = blockIdx.y * 128, col0 = blockIdx.x * 128;
  const int mBase = (wv >> 1) * 64, nBase = (wv & 1) * 64;
  const int lane15 = lane & 15;
  const int aoff = (MODE == 1) ? (col0 >> 8) * 128 : 0;

  f32x4 acc[4][4];
#pragma unroll
  for (int m = 0; m < 4; ++m)
#pragma unroll
    for (int n = 0; n < 4; ++n) acc[m][n] = (f32x4){0.f, 0.f, 0.f, 0.f};

  int rS[2], cS[2], dS[2];
#pragma unroll
  for (int c = 0; c < 2; ++c) {
    int p = c * 4096 + tid * 16;
    int r = p >> 6, u = (p >> 4) & 3;
    int f = (r & 3) ^ ((r >> 2) & 3);
    rS[c] = r; cS[c] = (u ^ f) * 8; dS[c] = c * 2048 + tid * 8;
  }
  const int fR = (lane & 3) ^ ((lane >> 2) & 3);
  const int uprime = (((lane >> 4) ^ fR) * 8);

  for (int k0 = 0; k0 < K; k0 += 32) {
#pragma unroll
    for (int c = 0; c < 2; ++c) {
      size_t ga = (size_t)(row0 + rS[c]) * lda + aoff + k0 + cS[c];
      size_t gb = (size_t)(col0 + rS[c]) * K + k0 + cS[c];
      __builtin_amdgcn_global_load_lds((const __attribute__((address_space(1))) void*)(A + ga),
                                       (__attribute__((address_space(3))) void*)(sA + dS[c]), 16, 0, 0);
      __builtin_amdgcn_global_load_lds((const __attribute__((address_space(1))) void*)(B + gb),
                                       (__attribute__((address_space(3))) void*)(sB + dS[c]), 16, 0, 0);
    }
    __syncthreads();

    short8 a[4], b[4];
#pragma unroll
    for (int m = 0; m < 4; ++m) {
      int ia = (mBase + m * 16 + lane15) * 32 + uprime;
      a[m] = *reinterpret_cast<const short8*>(sA + ia);
      int ib = (nBase + m * 16 + lane15) * 32 + uprime;
      b[m] = *reinterpret_cast<const short8*>(sB + ib);
    }
#pragma unroll
    for (int m = 0; m < 4; ++m)
#pragma unroll
      for (int n = 0; n < 4; ++n)
        acc[m][n] = __builtin_amdgcn_mfma_f32_16x16x32_bf16(a[m], b[n], acc[m][n], 0, 0, 0);
    __syncthreads();
  }

  const int head = col0 >> 8;
  const int q = ((col0 >> 6) & 2) | (nBase >> 6);
  float asv[4], adv[4];
  if (MODE == 0) {
#pragma unroll
    for (int n = 0; n < 4; ++n) {
      int cc = col0 + nBase + n * 16 + lane15;
      asv[n] = a_s[cc];
      adv[n] = a_d[cc];
    }
  }

  // C/D layout: col = lane&15, row = (lane>>4)*4 + j  [verified m89]
#pragma unroll
  for (int m = 0; m < 4; ++m) {
    int rr = row0 + mBase + m * 16 + (lane >> 4) * 4;
#pragma unroll
    for (int j = 0; j < 4; ++j) {
      if (MODE == 1) {
#pragma unroll
        for (int n = 0; n < 4; ++n) {
          int cc = col0 + nBase + n * 16 + lane15;
          float v = acc[m][n][j] + bias[cc];
          v = v > 0.f ? v : __expf(v) - 1.f;       // ELU
          OutBf[(size_t)(rr + j) * N + cc] = f2bf(v);
        }
      } else {
        // alpha partials (shfl reduce, one writer per slot)
        float ps = 0.f, pd = 0.f;
#pragma unroll
        for (int n = 0; n < 4; ++n) {
          float v = acc[m][n][j];
          ps = fmaf(v, asv[n], ps);
          pd = fmaf(v, adv[n], pd);
        }
        ps += __shfl_xor(ps, 1); pd += __shfl_xor(pd, 1);
        ps += __shfl_xor(ps, 2); pd += __shfl_xor(pd, 2);
        ps += __shfl_xor(ps, 4); pd += __shfl_xor(pd, 4);
        ps += __shfl_xor(ps, 8); pd += __shfl_xor(pd, 8);
        if (lane15 == 0) {
          asrcP[(size_t)(rr + j) * 16 + head * 4 + q] = ps;
          adstP[(size_t)(rr + j) * 16 + head * 4 + q] = pd;
        }
        // fp8 pack: 16-lane transpose (lane t gets cols 4t..4t+3, n = t>>2)
        int src = (lane & 48) | ((lane15 << 2) & 15);
        float c0 = 0.f, c1 = 0.f, c2 = 0.f, c3 = 0.f;
#pragma unroll
        for (int nn = 0; nn < 4; ++nn) {
          float t0 = __shfl(acc[m][nn][j], src + 0);
          float t1 = __shfl(acc[m][nn][j], src + 1);
          float t2 = __shfl(acc[m][nn][j], src + 2);
          float t3 = __shfl(acc[m][nn][j], src + 3);
          if ((lane15 >> 2) == nn) { c0 = t0; c1 = t1; c2 = t2; c3 = t3; }
        }
        int w = __builtin_amdgcn_cvt_pk_fp8_f32(c0, c1, 0, false);
        w = __builtin_amdgcn_cvt_pk_fp8_f32(c2, c3, w, true);
        Out8[(size_t)(rr + j) * (N >> 2) + ((col0 + nBase) >> 2) + lane15] = (unsigned int)w;
      }
    }
  }
}

// ---------------- GAT aggregation of fp8 h2: wave/(node,head), two-pass softmax ------
__global__ __launch_bounds__(256) void k_agg4(const unsigned int* __restrict__ h8,
                                              const float* __restrict__ asrcP,
                                              const float* __restrict__ adstP,
                                              const int* __restrict__ row_ptr,
                                              const int* __restrict__ csr_src, const float* __restrict__ bias,
                                              unsigned short* __restrict__ outHi) {
  int wid = (blockIdx.x * 256 + threadIdx.x) >> 6;
  int lane = threadIdx.x & 63;
  int node = wid >> 2, hd = wid & 3;
  int beg = row_ptr[node], end = row_ptr[node + 1];
  float4 dq = *reinterpret_cast<const float4*>(&adstP[(size_t)node * 16 + hd * 4]);
  float adn = dq.x + dq.y + dq.z + dq.w;
  // pass 1: true max (broadcast loads only)
  float m = -INFINITY;
  for (int e = beg; e < end; ++e) {
    int sidx = csr_src[e];
    float4 sq = *reinterpret_cast<const float4*>(&asrcP[(size_t)sidx * 16 + hd * 4]);
    float a = (sq.x + sq.y + sq.z + sq.w) + adn;
    a = a > 0.f ? a : NEG_SLOPE * a;
    m = fmaxf(m, a);
  }
  // pass 2: accumulate, no rescale chain
  float s = 0.f, ax = 0.f, ay = 0.f, az = 0.f, aw = 0.f;
  for (int e = beg; e < end; ++e) {
    int sidx = csr_src[e];
    float4 sq = *reinterpret_cast<const float4*>(&asrcP[(size_t)sidx * 16 + hd * 4]);
    float a = (sq.x + sq.y + sq.z + sq.w) + adn;
    a = a > 0.f ? a : NEG_SLOPE * a;
    float p = __expf(a - m);
    unsigned int dw = h8[(size_t)sidx * 256 + hd * 64 + lane];
    f32x2 lo = __builtin_amdgcn_cvt_pk_f32_fp8(dw, false);
    f32x2 hi = __builtin_amdgcn_cvt_pk_f32_fp8(dw, true);
    s += p;
    ax = fmaf(p, lo.x, ax);
    ay = fmaf(p, lo.y, ay);
    az = fmaf(p, hi.x, az);
    aw = fmaf(p, hi.y, aw);
  }
  float inv = 1.f / s;
  int fo = hd * HID + lane * 4;
  float4 bv = *reinterpret_cast<const float4*>(&bias[fo]);
  float4 o;
  o.x = ax * inv + bv.x; o.y = ay * inv + bv.y; o.z = az * inv + bv.z; o.w = aw * inv + bv.w;
  // ELU
  o.x = o.x > 0.f ? o.x : __expf(o.x) - 1.f;
  o.y = o.y > 0.f ? o.y : __expf(o.y) - 1.f;
  o.z = o.z > 0.f ? o.z : __expf(o.z) - 1.f;
  o.w = o.w > 0.f ? o.w : __expf(o.w) - 1.f;
  ushort4 hh;
  hh.x = f2bf(o.x); hh.y = f2bf(o.y); hh.z = f2bf(o.z); hh.w = f2bf(o.w);
  *reinterpret_cast<ushort4*>(&outHi[(size_t)node * FDIM + fo]) = hh;
}

// ---------------- layer-3 MFMA GEMM: [N,1024](bf16) @ w3t[16,1024]^T + alpha3 --------
__global__ __launch_bounds__(256) void k_gemm_n16(const unsigned short* __restrict__ A,
                                                  const unsigned short* __restrict__ w3t,
                                                  const float* __restrict__ a_s,
                                                  const float* __restrict__ a_d,
                                                  float* __restrict__ C,
                                                  float* __restrict__ asrc,
                                                  float* __restrict__ adst) {
  int wave = (blockIdx.x * 256 + threadIdx.x) >> 6;   // 0..767
  int lane = threadIdx.x & 63;
  int lane15 = lane & 15;
  int row0 = wave * 16;
  int kg = (lane >> 4) * 8;
  f32x4 acc = (f32x4){0.f, 0.f, 0.f, 0.f};
  const unsigned short* Ar = A + (size_t)(row0 + lane15) * FDIM + kg;
  const unsigned short* Br = w3t + (size_t)lane15 * FDIM + kg;
  for (int k0 = 0; k0 < FDIM; k0 += 32) {
    short8 a = *reinterpret_cast<const short8*>(Ar + k0);
    short8 b = *reinterpret_cast<const short8*>(Br + k0);
    acc = __builtin_amdgcn_mfma_f32_16x16x32_bf16(a, b, acc, 0, 0, 0);
  }
  float asv = a_s[lane15], adv = a_d[lane15];
  int rbase = row0 + (lane >> 4) * 4;
#pragma unroll
  for (int j = 0; j < 4; ++j) {
    float v = acc[j];
    C[(size_t)(rbase + j) * EMB + lane15] = v;
    float ps = v * asv, pd = v * adv;
    ps += __shfl_xor(ps, 1); pd += __shfl_xor(pd, 1);
    ps += __shfl_xor(ps, 2); pd += __shfl_xor(pd, 2);
    ps += __shfl_xor(ps, 4); pd += __shfl_xor(pd, 4);
    ps += __shfl_xor(ps, 8); pd += __shfl_xor(pd, 8);
    if (lane15 == 0) { asrc[rbase + j] = ps; adst[rbase + j] = pd; }
  }
}

// layer-3 aggregation (16 thr/node, two-pass) + fused q + z hi/lo bf16 ---------------
__global__ __launch_bounds__(256) void k_agg1(const float* __restrict__ h3, const float* __restrict__ asrc,
                                              const float* __restrict__ adst, const int* __restrict__ row_ptr,
                                              const int* __restrict__ csr_src, const float* __restrict__ bias,
                                              const float* __restrict__ centers,
                                              float* __restrict__ z, float* __restrict__ qout,
                                              unsigned short* __restrict__ zh,
                                              unsigned short* __restrict__ zl) {
  int idx = blockIdx.x * 256 + threadIdx.x;
  int node = idx >> 4, f = idx & 15;
  if (node >= N_NODES) return;
  int beg = row_ptr[node], end = row_ptr[node + 1];
  float adn = adst[node];
  float m = -INFINITY;
  for (int e = beg; e < end; ++e) {
    float a = asrc[csr_src[e]] + adn;
    a = a > 0.f ? a : NEG_SLOPE * a;
    m = fmaxf(m, a);
  }
  float s = 0.f, acc = 0.f;
  for (int e = beg; e < end; ++e) {
    int sidx = csr_src[e];
    float a = asrc[sidx] + adn;
    a = a > 0.f ? a : NEG_SLOPE * a;
    float p = __expf(a - m);
    s += p;
    acc = fmaf(p, h3[sidx * EMB + f], acc);
  }
  float zv = acc / s + bias[f];
  z[node * EMB + f] = zv;
  unsigned short hv = f2bf(zv);
  zh[node * EMB + f] = hv;
  zl[node * EMB + f] = f2bf(zv - bf2f(hv));
  float d0 = zv - centers[f];       d0 *= d0;
  float d1 = zv - centers[EMB + f]; d1 *= d1;
  d0 += __shfl_xor(d0, 1); d1 += __shfl_xor(d1, 1);
  d0 += __shfl_xor(d0, 2); d1 += __shfl_xor(d1, 2);
  d0 += __shfl_xor(d0, 4); d1 += __shfl_xor(d1, 4);
  d0 += __shfl_xor(d0, 8); d1 += __shfl_xor(d1, 8);
  if (f == 0) {
    float q0 = 1.f / (1.f + d0), q1 = 1.f / (1.f + d1);
    float inv = 1.f / (q0 + q1);
    qout[node * 2 + 0] = q0 * inv;
    qout[node * 2 + 1] = q1 * inv;
  }
}

// ---------------- adjacency: sigmoid(z @ z^T) via MFMA, hi/lo 3-term -----------------
__global__ __launch_bounds__(256) void k_adj(const unsigned short* __restrict__ zh,
                                             const unsigned short* __restrict__ zl,
                                             float* __restrict__ adj) {
  int tid = threadIdx.x;
  int lane = tid & 63, wv = tid >> 6;
  int r0 = blockIdx.y * 128 + wv * 32, c0 = blockIdx.x * 128;
  int l15 = lane & 15, kg = lane >> 4;
  short8 zero = (short8){0, 0, 0, 0, 0, 0, 0, 0};
  short8 ah[2], al[2];
#pragma unroll
  for (int g = 0; g < 2; ++g) {
    int row = r0 + g * 16 + l15;
    if (kg < 2) {
      ah[g] = *reinterpret_cast<const short8*>(&zh[(size_t)row * EMB + kg * 8]);
      al[g] = *reinterpret_cast<const short8*>(&zl[(size_t)row * EMB + kg * 8]);
    } else { ah[g] = zero; al[g] = zero; }
  }
  short8 bh[8], bl[8];
#pragma unroll
  for (int n = 0; n < 8; ++n) {
    int col = c0 + n * 16 + l15;
    if (kg < 2) {
      bh[n] = *reinterpret_cast<const short8*>(&zh[(size_t)col * EMB + kg * 8]);
      bl[n] = *reinterpret_cast<const short8*>(&zl[(size_t)col * EMB + kg * 8]);
    } else { bh[n] = zero; bl[n] = zero; }
  }
#pragma unroll
  for (int g = 0; g < 2; ++g) {
    int rbase = r0 + g * 16 + kg * 4;
#pragma unroll
    for (int n = 0; n < 8; ++n) {
      f32x4 acc = (f32x4){0.f, 0.f, 0.f, 0.f};
      acc = __builtin_amdgcn_mfma_f32_16x16x32_bf16(ah[g], bh[n], acc, 0, 0, 0);
      acc = __builtin_amdgcn_mfma_f32_16x16x32_bf16(ah[g], bl[n], acc, 0, 0, 0);
      acc = __builtin_amdgcn_mfma_f32_16x16x32_bf16(al[g], bh[n], acc, 0, 0, 0);
      int cc = c0 + n * 16 + l15;
#pragma unroll
      for (int j = 0; j < 4; ++j) {
        float v = 1.f / (1.f + __expf(-acc[j]));
        adj[(size_t)(rbase + j) * N_NODES + cc] = v;
      }
    }
  }
}

// ====================================================================================
extern "C" void kernel_launch(void* const* d_in, const int* in_sizes, int n_in,
                              void* d_out, int out_size, void* d_ws, size_t ws_size,
                              hipStream_t stream) {
  const float* x   = (const float*)d_in[0];
  const int*   ei  = (const int*)d_in[1];
  const float* W1  = (const float*)d_in[2];
  const float* as1 = (const float*)d_in[3];
  const float* ad1 = (const float*)d_in[4];
  const float* b1  = (const float*)d_in[5];
  const float* W2  = (const float*)d_in[6];
  const float* as2 = (const float*)d_in[7];
  const float* ad2 = (const float*)d_in[8];
  const float* b2  = (const float*)d_in[9];
  const float* W3  = (const float*)d_in[10];
  const float* as3 = (const float*)d_in[11];
  const float* ad3 = (const float*)d_in[12];
  const float* b3  = (const float*)d_in[13];
  const float* centers = (const float*)d_in[14];
  float* out = (float*)d_out;

  char* ws = (char*)d_ws;
  size_t off = 0;
  auto alloc = [&](size_t bytes) { void* p = ws + off; off = (off + bytes + 255) & ~(size_t)255; return p; };
  int* cnt       = (int*)alloc((size_t)N_NODES * 4);           // cnt+cur contiguous
  int* cur       = (int*)alloc((size_t)N_NODES * 4);
  int* row_ptr   = (int*)alloc((size_t)(N_NODES + 1) * 4);
  int* bsum      = (int*)alloc(64 * 4);
  int* csr_src   = (int*)alloc((size_t)EP_EDGES * 4);
  float* asrcA   = (float*)alloc((size_t)N_NODES * HEADS * 4);
  float* adstA   = (float*)alloc((size_t)N_NODES * HEADS * 4);
  float* asrcP   = (float*)alloc((size_t)N_NODES * 16 * 4);    // per-(row,head,quarter)
  float* adstP   = (float*)alloc((size_t)N_NODES * 16 * 4);
  float* asrc3   = (float*)alloc((size_t)N_NODES * 4);
  float* adst3   = (float*)alloc((size_t)N_NODES * 4);
  float* wa      = (float*)alloc(1024 * 4);
  unsigned short* xbf    = (unsigned short*)alloc((size_t)N_NODES * 128 * 2);
  unsigned short* aggxHi = (unsigned short*)alloc((size_t)N_NODES * 512 * 2);
  unsigned short* h1bf   = (unsigned short*)alloc((size_t)N_NODES * FDIM * 2);
  unsigned int*   h8     = (unsigned int*)alloc((size_t)N_NODES * FDIM);        // h2 fp8
  unsigned short* agg2Hi = (unsigned short*)alloc((size_t)N_NODES * FDIM * 2);
  unsigned short* w1tHi  = (unsigned short*)alloc((size_t)FDIM * 128 * 2);
  unsigned short* w2tHi  = (unsigned short*)alloc((size_t)FDIM * FDIM * 2);
  unsigned short* w3t    = (unsigned short*)alloc((size_t)16 * FDIM * 2);
  unsigned short* zh     = (unsigned short*)alloc((size_t)N_NODES * EMB * 2);
  unsigned short* zl     = (unsigned short*)alloc((size_t)N_NODES * EMB * 2);
  float* bufZ    = (float*)alloc((size_t)N_NODES * EMB * 4);

  hipMemsetAsync(cnt, 0, (size_t)N_NODES * 8, stream);                 // cnt + cur

  // ---- K1: hist ∥ prep (x->bf16, W1t, W2t, wa, W3t)
  k_hist_prep<<<dim3(HIST_BLKS + 1536 + 128 + 1024 + 2), dim3(256), 0, stream>>>(
      ei, cnt, x, xbf, W1, w1tHi, W2, w2tHi, as1, ad1, wa, W3, w3t);

  // ---- K2: scan1 ∥ alpha_x
  k_scan_alpha<<<dim3(12 + 48), dim3(1024), 0, stream>>>(
      cnt, row_ptr, bsum, x, wa, asrcA, adstA);

  // ---- K3/K4: finish scan, scatter
  k_scan23<<<dim3(N_NODES / 256), dim3(256), 0, stream>>>(row_ptr, bsum);
  k_scatter<<<dim3((EP_EDGES + 255) / 256), dim3(256), 0, stream>>>(ei, row_ptr, cur, csr_src);

  // ---- layer 1 (commuted): aggregate x (all heads/wave), project (+bias+ELU)
  k_aggx<<<dim3(N_NODES / 4), dim3(256), 0, stream>>>(xbf, asrcA, adstA, row_ptr, csr_src, aggxHi);
  k_gemm<1><<<dim3(FDIM / 128, N_NODES / 128), dim3(256), 0, stream>>>(
      aggxHi, w1tHi, h1bf, nullptr, b1, nullptr, nullptr, nullptr, nullptr, N_NODES, FDIM, 128, 512);

  // ---- layer 2: bf16 GEMM -> fp8 h2 direct + fused non-atomic alpha partials
  k_gemm<0><<<dim3(FDIM / 128, N_NODES / 128), dim3(256), 0, stream>>>(
      h1bf, w2tHi, nullptr, h8, nullptr, as2, ad2, asrcP, adstP, N_NODES, FDIM, FDIM, FDIM);
  k_agg4<<<dim3(N_NODES), dim3(256), 0, stream>>>(h8, asrcP, adstP, row_ptr, csr_src, b2, agg2Hi);

  // ---- layer 3: MFMA GEMM (alpha fused); agg1 fuses q + z hi/lo
  k_gemm_n16<<<dim3(N_NODES / 64), dim3(256), 0, stream>>>(
      agg2Hi, w3t, as3, ad3, bufZ, asrc3, adst3);
  float* adj = out + (size_t)N_NODES * EMB;
  float* q   = adj + (size_t)N_NODES * N_NODES;
  k_agg1<<<dim3(N_NODES * EMB / 256), dim3(256), 0, stream>>>(
      bufZ, asrc3, adst3, row_ptr, csr_src, b3, centers, out, q, zh, zl);

  // ---- adjacency decoder: MFMA z@z^T
  k_adj<<<dim3(N_NODES / 128, N_NODES / 128), dim3(256), 0, stream>>>(zh, zl, adj);
}

// Round 13
// 391.871 us; speedup vs baseline: 1.2609x; 1.2609x over previous
//
#include <hip/hip_runtime.h>
#include <hip/hip_bf16.h>
#include <math.h>

#define N_NODES 12288
#define N_EDGES 196608
#define EP_EDGES (N_EDGES + N_NODES)   // 208896 edges incl. self loops
#define HEADS 4
#define HID 256
#define FDIM 1024                      // HEADS*HID
#define EMB 16
#define NEG_SLOPE 0.2f

typedef __attribute__((ext_vector_type(8))) short short8;
typedef __attribute__((ext_vector_type(4))) float f32x4;
typedef __attribute__((ext_vector_type(2))) float f32x2;

// bf16 helpers (RNE)
__device__ __forceinline__ unsigned short f2bf(float f) {
  unsigned int u = __float_as_uint(f);
  u = (u + 0x7FFFu + ((u >> 16) & 1u)) >> 16;
  return (unsigned short)u;
}
__device__ __forceinline__ float bf2f(unsigned short h) {
  return __uint_as_float(((unsigned int)h) << 16);
}

// ---------------- K1: hist ∥ x->bf16 ∥ W1t ∥ W2t ∥ wa ∥ W3t -------------------------
__device__ __forceinline__ void t_tile_hi(const float* __restrict__ W,
                                          unsigned short* __restrict__ Th,
                                          int K, int N, int k0, int n0,
                                          int t, float (*tile)[33]) {
  int rr = t >> 3, cc = (t & 7) * 4;
  float4 v = *reinterpret_cast<const float4*>(&W[(size_t)(k0 + rr) * N + n0 + cc]);
  tile[rr][cc + 0] = v.x; tile[rr][cc + 1] = v.y; tile[rr][cc + 2] = v.z; tile[rr][cc + 3] = v.w;
  __syncthreads();
  ushort4 h;
  h.x = f2bf(tile[cc + 0][rr]);
  h.y = f2bf(tile[cc + 1][rr]);
  h.z = f2bf(tile[cc + 2][rr]);
  h.w = f2bf(tile[cc + 3][rr]);
  *reinterpret_cast<ushort4*>(&Th[(size_t)(n0 + rr) * K + k0 + cc]) = h;
}

#define HIST_BLKS (EP_EDGES / 256)     // 816
__global__ __launch_bounds__(256) void k_hist_prep(const int* __restrict__ ei,
                                                   int* __restrict__ cnt,
                                                   const float* __restrict__ x,
                                                   unsigned short* __restrict__ xbf,
                                                   const float* __restrict__ W1,
                                                   unsigned short* __restrict__ w1tHi,
                                                   const float* __restrict__ W2,
                                                   unsigned short* __restrict__ w2tHi,
                                                   const float* __restrict__ as1,
                                                   const float* __restrict__ ad1,
                                                   float* __restrict__ wa,
                                                   const float* __restrict__ W3,
                                                   unsigned short* __restrict__ w3t) {
  __shared__ float tile[32][33];
  int b = blockIdx.x, t = threadIdx.x;
  if (b < HIST_BLKS) {
    int i = b * 256 + t;
    if (i < EP_EDGES) {
      int d = (i < N_EDGES) ? ei[N_EDGES + i] : (i - N_EDGES);
      atomicAdd(&cnt[d], 1);
    }
  } else if (b < HIST_BLKS + 1536) {               // x convert
    int i = (b - HIST_BLKS) * 256 + t;
    float4 v = *reinterpret_cast<const float4*>(&x[(size_t)i * 4]);
    ushort4 h;
    h.x = f2bf(v.x); h.y = f2bf(v.y); h.z = f2bf(v.z); h.w = f2bf(v.w);
    *reinterpret_cast<ushort4*>(&xbf[(size_t)i * 4]) = h;
  } else if (b < HIST_BLKS + 1536 + 128) {         // W1 [128,1024] -> [1024,128] bf16
    int tt = b - HIST_BLKS - 1536;
    t_tile_hi(W1, w1tHi, 128, FDIM, (tt >> 5) * 32, (tt & 31) * 32, t, tile);
  } else if (b < HIST_BLKS + 1536 + 128 + 1024) {  // W2 [1024,1024] -> [1024,1024] bf16
    int tt = b - HIST_BLKS - 1536 - 128;
    t_tile_hi(W2, w2tHi, FDIM, FDIM, (tt >> 5) * 32, (tt & 31) * 32, t, tile);
  } else if (b == HIST_BLKS + 1536 + 128 + 1024) { // wa GEMV
    for (int idx = t; idx < 1024; idx += 256) {
      int sd = idx >> 9, h = (idx >> 7) & 3, k = idx & 127;
      const float* av = sd ? ad1 : as1;
      float acc = 0.f;
      for (int f = 0; f < 256; ++f)
        acc = fmaf(W1[(size_t)k * FDIM + h * 256 + f], av[h * 256 + f], acc);
      wa[idx] = acc;
    }
  } else {                                         // W3 [1024,16] -> w3t [16,1024] bf16
    for (int idx = t; idx < 16384; idx += 256) {
      int c = idx >> 10, k = idx & 1023;
      w3t[idx] = f2bf(W3[(size_t)k * 16 + c]);
    }
  }
}

// ---------------- K2: scan1 (blocks 0-11) ∥ alpha_x (blocks 12-59), 1024 thr --------
__global__ __launch_bounds__(1024) void k_scan_alpha(const int* __restrict__ cnt,
                                                     int* __restrict__ row_ptr,
                                                     int* __restrict__ bsum,
                                                     const float* __restrict__ x,
                                                     const float* __restrict__ wa,
                                                     float* __restrict__ asrc,
                                                     float* __restrict__ adst) {
  __shared__ int sd[1024];
  int tid = threadIdx.x;
  if (blockIdx.x < 12) {                           // exclusive scan of cnt
    int gid = blockIdx.x * 1024 + tid;
    int v = cnt[gid];
    sd[tid] = v;
    __syncthreads();
    for (int d = 1; d < 1024; d <<= 1) {
      int t2 = (tid >= d) ? sd[tid - d] : 0;
      __syncthreads();
      sd[tid] += t2;
      __syncthreads();
    }
    row_ptr[gid] = sd[tid] - v;
    if (tid == 1023) bsum[blockIdx.x] = sd[1023];
  } else {                                         // layer-1 alphas from x
    int id = (blockIdx.x - 12) * 1024 + tid;       // N*4
    int n = id >> 2, h = id & 3;
    const float* wsv = wa + h * 128;
    const float* wdv = wa + 512 + h * 128;
    const float* xr = x + (size_t)n * 128;
    float accs = 0.f, accd = 0.f;
#pragma unroll
    for (int k = 0; k < 128; k += 4) {
      float4 xv = *reinterpret_cast<const float4*>(&xr[k]);
      float4 s4 = *reinterpret_cast<const float4*>(&wsv[k]);
      float4 d4 = *reinterpret_cast<const float4*>(&wdv[k]);
      accs = fmaf(xv.x, s4.x, fmaf(xv.y, s4.y, fmaf(xv.z, s4.z, fmaf(xv.w, s4.w, accs))));
      accd = fmaf(xv.x, d4.x, fmaf(xv.y, d4.y, fmaf(xv.z, d4.z, fmaf(xv.w, d4.w, accd))));
    }
    asrc[n * 4 + h] = accs;
    adst[n * 4 + h] = accd;
  }
}

// ---------------- K3: add block offsets (scan2 inlined per-thread) ------------------
__global__ void k_scan23(int* __restrict__ row_ptr, const int* __restrict__ bsum) {
  int gid = blockIdx.x * 256 + threadIdx.x;
  int blk = gid >> 10;
  int boffv = 0;
  for (int j = 0; j < blk; ++j) boffv += bsum[j];
  row_ptr[gid] += boffv;
  if (gid == 0) {
    int tot = 0;
    for (int j = 0; j < 12; ++j) tot += bsum[j];
    row_ptr[N_NODES] = tot;
  }
}

__global__ void k_scatter(const int* __restrict__ ei, const int* __restrict__ row_ptr,
                          int* __restrict__ cur, int* __restrict__ csr_src) {
  int i = blockIdx.x * 256 + threadIdx.x;
  if (i >= EP_EDGES) return;
  int s, d;
  if (i < N_EDGES) { s = ei[i]; d = ei[N_EDGES + i]; }
  else             { s = i - N_EDGES; d = s; }
  int pos = row_ptr[d] + atomicAdd(&cur[d], 1);
  csr_src[pos] = s;
}

// ---------------- layer-1 aggregation: ONE wave per node, ALL 4 heads (online) -------
__global__ __launch_bounds__(256) void k_aggx(const unsigned short* __restrict__ xbf,
                                              const float* __restrict__ asrc,
                                              const float* __restrict__ adst,
                                              const int* __restrict__ row_ptr,
                                              const int* __restrict__ csr_src,
                                              unsigned short* __restrict__ outHi) {
  int node = (blockIdx.x * 256 + threadIdx.x) >> 6;
  int lane = threadIdx.x & 63;
  int beg = row_ptr[node], end = row_ptr[node + 1];
  float4 adn = *reinterpret_cast<const float4*>(&adst[node * 4]);
  float m0 = -INFINITY, m1 = -INFINITY, m2 = -INFINITY, m3 = -INFINITY;
  float s0 = 0.f, s1 = 0.f, s2 = 0.f, s3 = 0.f;
  float a0x = 0.f, a0y = 0.f, a1x = 0.f, a1y = 0.f;
  float a2x = 0.f, a2y = 0.f, a3x = 0.f, a3y = 0.f;
  for (int e = beg; e < end; ++e) {
    int sidx = csr_src[e];
    float4 av = *reinterpret_cast<const float4*>(&asrc[sidx * 4]);
    ushort2 hu = *reinterpret_cast<const ushort2*>(&xbf[(size_t)sidx * 128 + lane * 2]);
    float hx = bf2f(hu.x), hy = bf2f(hu.y);
    float a, nm, sc, p;
    a = av.x + adn.x; a = a > 0.f ? a : NEG_SLOPE * a;
    nm = fmaxf(m0, a); sc = __expf(m0 - nm); p = __expf(a - nm); m0 = nm;
    s0 = s0 * sc + p; a0x = a0x * sc + p * hx; a0y = a0y * sc + p * hy;
    a = av.y + adn.y; a = a > 0.f ? a : NEG_SLOPE * a;
    nm = fmaxf(m1, a); sc = __expf(m1 - nm); p = __expf(a - nm); m1 = nm;
    s1 = s1 * sc + p; a1x = a1x * sc + p * hx; a1y = a1y * sc + p * hy;
    a = av.z + adn.z; a = a > 0.f ? a : NEG_SLOPE * a;
    nm = fmaxf(m2, a); sc = __expf(m2 - nm); p = __expf(a - nm); m2 = nm;
    s2 = s2 * sc + p; a2x = a2x * sc + p * hx; a2y = a2y * sc + p * hy;
    a = av.w + adn.w; a = a > 0.f ? a : NEG_SLOPE * a;
    nm = fmaxf(m3, a); sc = __expf(m3 - nm); p = __expf(a - nm); m3 = nm;
    s3 = s3 * sc + p; a3x = a3x * sc + p * hx; a3y = a3y * sc + p * hy;
  }
  size_t base = (size_t)node * 512 + lane * 2;
  ushort2 o;
  float inv;
  inv = 1.f / s0; o.x = f2bf(a0x * inv); o.y = f2bf(a0y * inv);
  *reinterpret_cast<ushort2*>(&outHi[base + 0 * 128]) = o;
  inv = 1.f / s1; o.x = f2bf(a1x * inv); o.y = f2bf(a1y * inv);
  *reinterpret_cast<ushort2*>(&outHi[base + 1 * 128]) = o;
  inv = 1.f / s2; o.x = f2bf(a2x * inv); o.y = f2bf(a2y * inv);
  *reinterpret_cast<ushort2*>(&outHi[base + 2 * 128]) = o;
  inv = 1.f / s3; o.x = f2bf(a3x * inv); o.y = f2bf(a3y * inv);
  *reinterpret_cast<ushort2*>(&outHi[base + 3 * 128]) = o;
}

// ---------------- bf16 MFMA GEMM: C[M,N] = A[M,K] @ B[N,K]^T, 128x128, BK=32 ---------
// MODE 1: head-sliced A (lda, aoff), bias+ELU, bf16 out.
// MODE 0: plain bf16 out + NON-ATOMIC per-(row,head,quarter) alpha partials.
template <int MODE>
__global__ __launch_bounds__(256) void k_gemm(const unsigned short* __restrict__ A,
                                              const unsigned short* __restrict__ B,
                                              unsigned short* __restrict__ Out,
                                              const float* __restrict__ bias,
                                              const float* __restrict__ a_s,
                                              const float* __restrict__ a_d,
                                              float* __restrict__ asrcP,
                                              float* __restrict__ adstP,
                                              int M, int N, int K, int lda) {
  __shared__ unsigned short sA[128 * 32], sB[128 * 32];
  const int tid = threadIdx.x;
  const int lane = tid & 63, wv = tid >> 6;
  const int row0 = blockIdx.y * 128, col0 = blockIdx.x * 128;
  const int mBase = (wv >> 1) * 64, nBase = (wv & 1) * 64;
  const int lane15 = lane & 15;
  const int aoff = (MODE == 1) ? (col0 >> 8) * 128 : 0;

  f32x4 acc[4][4];
#pragma unroll
  for (int m = 0; m < 4; ++m)
#pragma unroll
    for (int n = 0; n < 4; ++n) acc[m][n] = (f32x4){0.f, 0.f, 0.f, 0.f};

  int rS[2], cS[2], dS[2];
#pragma unroll
  for (int c = 0; c < 2; ++c) {
    int p = c * 4096 + tid * 16;
    int r = p >> 6, u = (p >> 4) & 3;
    int f = (r & 3) ^ ((r >> 2) & 3);
    rS[c] = r; cS[c] = (u ^ f) * 8; dS[c] = c * 2048 + tid * 8;
  }
  const int fR = (lane & 3) ^ ((lane >> 2) & 3);
  const int uprime = (((lane >> 4) ^ fR) * 8);

  for (int k0 = 0; k0 < K; k0 += 32) {
#pragma unroll
    for (int c = 0; c < 2; ++c) {
      size_t ga = (size_t)(row0 + rS[c]) * lda + aoff + k0 + cS[c];
      size_t gb = (size_t)(col0 + rS[c]) * K + k0 + cS[c];
      __builtin_amdgcn_global_load_lds((const __attribute__((address_space(1))) void*)(A + ga),
                                       (__attribute__((address_space(3))) void*)(sA + dS[c]), 16, 0, 0);
      __builtin_amdgcn_global_load_lds((const __attribute__((address_space(1))) void*)(B + gb),
                                       (__attribute__((address_space(3))) void*)(sB + dS[c]), 16, 0, 0);
    }
    __syncthreads();

    short8 a[4], b[4];
#pragma unroll
    for (int m = 0; m < 4; ++m) {
      int ia = (mBase + m * 16 + lane15) * 32 + uprime;
      a[m] = *reinterpret_cast<const short8*>(sA + ia);
      int ib = (nBase + m * 16 + lane15) * 32 + uprime;
      b[m] = *reinterpret_cast<const short8*>(sB + ib);
    }
#pragma unroll
    for (int m = 0; m < 4; ++m)
#pragma unroll
      for (int n = 0; n < 4; ++n)
        acc[m][n] = __builtin_amdgcn_mfma_f32_16x16x32_bf16(a[m], b[n], acc[m][n], 0, 0, 0);
    __syncthreads();
  }

  const int head = col0 >> 8;
  const int q = ((col0 >> 6) & 2) | (nBase >> 6);
  float asv[4], adv[4];
  if (MODE == 0) {
#pragma unroll
    for (int n = 0; n < 4; ++n) {
      int cc = col0 + nBase + n * 16 + lane15;
      asv[n] = a_s[cc];
      adv[n] = a_d[cc];
    }
  }

  // C/D layout: col = lane&15, row = (lane>>4)*4 + j  [verified m89]
#pragma unroll
  for (int m = 0; m < 4; ++m) {
    int rr = row0 + mBase + m * 16 + (lane >> 4) * 4;
#pragma unroll
    for (int j = 0; j < 4; ++j) {
      if (MODE == 1) {
#pragma unroll
        for (int n = 0; n < 4; ++n) {
          int cc = col0 + nBase + n * 16 + lane15;
          float v = acc[m][n][j] + bias[cc];
          v = v > 0.f ? v : __expf(v) - 1.f;       // ELU
          Out[(size_t)(rr + j) * N + cc] = f2bf(v);
        }
      } else {
        float ps = 0.f, pd = 0.f;
#pragma unroll
        for (int n = 0; n < 4; ++n) {
          int cc = col0 + nBase + n * 16 + lane15;
          float v = acc[m][n][j];
          Out[(size_t)(rr + j) * N + cc] = f2bf(v);
          ps = fmaf(v, asv[n], ps);
          pd = fmaf(v, adv[n], pd);
        }
        ps += __shfl_xor(ps, 1); pd += __shfl_xor(pd, 1);
        ps += __shfl_xor(ps, 2); pd += __shfl_xor(pd, 2);
        ps += __shfl_xor(ps, 4); pd += __shfl_xor(pd, 4);
        ps += __shfl_xor(ps, 8); pd += __shfl_xor(pd, 8);
        if (lane15 == 0) {                          // exactly one writer per slot
          asrcP[(size_t)(rr + j) * 16 + head * 4 + q] = ps;
          adstP[(size_t)(rr + j) * 16 + head * 4 + q] = pd;
        }
      }
    }
  }
}

// ---------------- repack h2 bf16->fp8 ∥ reduce alpha quarters -----------------------
__global__ void k_repack8(const unsigned short* __restrict__ hbf,
                          unsigned int* __restrict__ h8,
                          const float* __restrict__ asrcP,
                          const float* __restrict__ adstP,
                          float* __restrict__ asrcR,
                          float* __restrict__ adstR) {
  int b = blockIdx.x;
  if (b < 12288) {                                 // N*FDIM/4/256
    int i = b * 256 + threadIdx.x;                 // one output dword = 4 fp8
    ushort4 v = *reinterpret_cast<const ushort4*>(&hbf[(size_t)i * 4]);
    int w = __builtin_amdgcn_cvt_pk_fp8_f32(bf2f(v.x), bf2f(v.y), 0, false);
    w = __builtin_amdgcn_cvt_pk_fp8_f32(bf2f(v.z), bf2f(v.w), w, true);
    h8[i] = (unsigned int)w;
  } else {                                         // reduce quarters: N*4 scalars
    int i = (b - 12288) * 256 + threadIdx.x;
    float4 sq = *reinterpret_cast<const float4*>(&asrcP[(size_t)i * 4]);
    asrcR[i] = sq.x + sq.y + sq.z + sq.w;
    float4 dq = *reinterpret_cast<const float4*>(&adstP[(size_t)i * 4]);
    adstR[i] = dq.x + dq.y + dq.z + dq.w;
  }
}

// ---------------- GAT aggregation of fp8 h2: ONE wave per node, 16 feat/lane ---------
// Lane l owns features [16l,16l+16) => head = l>>4; full 1KB row read contiguously.
__global__ __launch_bounds__(256) void k_agg4(const unsigned int* __restrict__ h8,
                                              const float* __restrict__ asrcR,
                                              const float* __restrict__ adstR,
                                              const int* __restrict__ row_ptr,
                                              const int* __restrict__ csr_src, const float* __restrict__ bias,
                                              unsigned short* __restrict__ outHi) {
  int node = (blockIdx.x * 256 + threadIdx.x) >> 6;
  int lane = threadIdx.x & 63;
  int hd = lane >> 4;
  int beg = row_ptr[node], end = row_ptr[node + 1];
  float adn = adstR[node * 4 + hd];
  float m = -INFINITY, s = 0.f;
  float acc[16];
#pragma unroll
  for (int k = 0; k < 16; ++k) acc[k] = 0.f;
  for (int e = beg; e < end; ++e) {
    int sidx = csr_src[e];
    float a = asrcR[sidx * 4 + hd] + adn;
    a = a > 0.f ? a : NEG_SLOPE * a;            // leaky_relu
    float nm = fmaxf(m, a);
    float sc = __expf(m - nm);                  // exp(-inf)=0 on first edge
    float p  = __expf(a - nm);
    m = nm;
    s = s * sc + p;
    uint4 dw = *reinterpret_cast<const uint4*>(h8 + (size_t)sidx * 256 + lane * 4);
#pragma unroll
    for (int d = 0; d < 4; ++d) {
      unsigned int w = (&dw.x)[d];
      f32x2 lo = __builtin_amdgcn_cvt_pk_f32_fp8(w, false);
      f32x2 hi = __builtin_amdgcn_cvt_pk_f32_fp8(w, true);
      acc[d * 4 + 0] = acc[d * 4 + 0] * sc + p * lo.x;
      acc[d * 4 + 1] = acc[d * 4 + 1] * sc + p * lo.y;
      acc[d * 4 + 2] = acc[d * 4 + 2] * sc + p * hi.x;
      acc[d * 4 + 3] = acc[d * 4 + 3] * sc + p * hi.y;
    }
  }
  float inv = 1.f / s;
  int fo = lane * 16;
#pragma unroll
  for (int d = 0; d < 4; ++d) {
    float4 bv = *reinterpret_cast<const float4*>(&bias[fo + d * 4]);
    float v0 = acc[d * 4 + 0] * inv + bv.x;
    float v1 = acc[d * 4 + 1] * inv + bv.y;
    float v2 = acc[d * 4 + 2] * inv + bv.z;
    float v3 = acc[d * 4 + 3] * inv + bv.w;
    v0 = v0 > 0.f ? v0 : __expf(v0) - 1.f;       // ELU
    v1 = v1 > 0.f ? v1 : __expf(v1) - 1.f;
    v2 = v2 > 0.f ? v2 : __expf(v2) - 1.f;
    v3 = v3 > 0.f ? v3 : __expf(v3) - 1.f;
    ushort4 st;
    st.x = f2bf(v0); st.y = f2bf(v1); st.z = f2bf(v2); st.w = f2bf(v3);
    *reinterpret_cast<ushort4*>(&outHi[(size_t)node * FDIM + fo + d * 4]) = st;
  }
}

// ---------------- layer-3 MFMA GEMM: [N,1024](bf16) @ w3t[16,1024]^T + alpha3 --------
__global__ __launch_bounds__(256) void k_gemm_n16(const unsigned short* __restrict__ A,
                                                  const unsigned short* __restrict__ w3t,
                                                  const float* __restrict__ a_s,
                                                  const float* __restrict__ a_d,
                                                  float* __restrict__ C,
                                                  float* __restrict__ asrc,
                                                  float* __restrict__ adst) {
  int wave = (blockIdx.x * 256 + threadIdx.x) >> 6;   // 0..767
  int lane = threadIdx.x & 63;
  int lane15 = lane & 15;
  int row0 = wave * 16;
  int kg = (lane >> 4) * 8;
  f32x4 acc = (f32x4){0.f, 0.f, 0.f, 0.f};
  const unsigned short* Ar = A + (size_t)(row0 + lane15) * FDIM + kg;
  const unsigned short* Br = w3t + (size_t)lane15 * FDIM + kg;
  for (int k0 = 0; k0 < FDIM; k0 += 32) {
    short8 a = *reinterpret_cast<const short8*>(Ar + k0);
    short8 b = *reinterpret_cast<const short8*>(Br + k0);
    acc = __builtin_amdgcn_mfma_f32_16x16x32_bf16(a, b, acc, 0, 0, 0);
  }
  float asv = a_s[lane15], adv = a_d[lane15];
  int rbase = row0 + (lane >> 4) * 4;
#pragma unroll
  for (int j = 0; j < 4; ++j) {
    float v = acc[j];
    C[(size_t)(rbase + j) * EMB + lane15] = v;
    float ps = v * asv, pd = v * adv;
    ps += __shfl_xor(ps, 1); pd += __shfl_xor(pd, 1);
    ps += __shfl_xor(ps, 2); pd += __shfl_xor(pd, 2);
    ps += __shfl_xor(ps, 4); pd += __shfl_xor(pd, 4);
    ps += __shfl_xor(ps, 8); pd += __shfl_xor(pd, 8);
    if (lane15 == 0) { asrc[rbase + j] = ps; adst[rbase + j] = pd; }
  }
}

// layer-3 aggregation (16 threads/node, online) + fused q + z hi/lo bf16 -------------
__global__ __launch_bounds__(256) void k_agg1(const float* __restrict__ h3, const float* __restrict__ asrc,
                                              const float* __restrict__ adst, const int* __restrict__ row_ptr,
                                              const int* __restrict__ csr_src, const float* __restrict__ bias,
                                              const float* __restrict__ centers,
                                              float* __restrict__ z, float* __restrict__ qout,
                                              unsigned short* __restrict__ zh,
                                              unsigned short* __restrict__ zl) {
  int idx = blockIdx.x * 256 + threadIdx.x;
  int node = idx >> 4, f = idx & 15;
  if (node >= N_NODES) return;
  int beg = row_ptr[node], end = row_ptr[node + 1];
  float adn = adst[node];
  float m = -INFINITY, s = 0.f, acc = 0.f;
  for (int e = beg; e < end; ++e) {
    int sidx = csr_src[e];
    float a = asrc[sidx] + adn;
    a = a > 0.f ? a : NEG_SLOPE * a;
    float nm = fmaxf(m, a);
    float sc = __expf(m - nm);
    float p  = __expf(a - nm);
    m = nm;
    s = s * sc + p;
    acc = acc * sc + p * h3[sidx * EMB + f];
  }
  float zv = acc / s + bias[f];
  z[node * EMB + f] = zv;
  unsigned short hv = f2bf(zv);
  zh[node * EMB + f] = hv;
  zl[node * EMB + f] = f2bf(zv - bf2f(hv));
  float d0 = zv - centers[f];       d0 *= d0;
  float d1 = zv - centers[EMB + f]; d1 *= d1;
  d0 += __shfl_xor(d0, 1); d1 += __shfl_xor(d1, 1);
  d0 += __shfl_xor(d0, 2); d1 += __shfl_xor(d1, 2);
  d0 += __shfl_xor(d0, 4); d1 += __shfl_xor(d1, 4);
  d0 += __shfl_xor(d0, 8); d1 += __shfl_xor(d1, 8);
  if (f == 0) {
    float q0 = 1.f / (1.f + d0), q1 = 1.f / (1.f + d1);
    float inv = 1.f / (q0 + q1);
    qout[node * 2 + 0] = q0 * inv;
    qout[node * 2 + 1] = q1 * inv;
  }
}

// ---------------- adjacency: sigmoid(z @ z^T) via MFMA, hi/lo 3-term -----------------
__global__ __launch_bounds__(256) void k_adj(const unsigned short* __restrict__ zh,
                                             const unsigned short* __restrict__ zl,
                                             float* __restrict__ adj) {
  int tid = threadIdx.x;
  int lane = tid & 63, wv = tid >> 6;
  int r0 = blockIdx.y * 128 + wv * 32, c0 = blockIdx.x * 128;
  int l15 = lane & 15, kg = lane >> 4;
  short8 zero = (short8){0, 0, 0, 0, 0, 0, 0, 0};
  short8 ah[2], al[2];
#pragma unroll
  for (int g = 0; g < 2; ++g) {
    int row = r0 + g * 16 + l15;
    if (kg < 2) {
      ah[g] = *reinterpret_cast<const short8*>(&zh[(size_t)row * EMB + kg * 8]);
      al[g] = *reinterpret_cast<const short8*>(&zl[(size_t)row * EMB + kg * 8]);
    } else { ah[g] = zero; al[g] = zero; }
  }
  short8 bh[8], bl[8];
#pragma unroll
  for (int n = 0; n < 8; ++n) {
    int col = c0 + n * 16 + l15;
    if (kg < 2) {
      bh[n] = *reinterpret_cast<const short8*>(&zh[(size_t)col * EMB + kg * 8]);
      bl[n] = *reinterpret_cast<const short8*>(&zl[(size_t)col * EMB + kg * 8]);
    } else { bh[n] = zero; bl[n] = zero; }
  }
#pragma unroll
  for (int g = 0; g < 2; ++g) {
    int rbase = r0 + g * 16 + kg * 4;
#pragma unroll
    for (int n = 0; n < 8; ++n) {
      f32x4 acc = (f32x4){0.f, 0.f, 0.f, 0.f};
      acc = __builtin_amdgcn_mfma_f32_16x16x32_bf16(ah[g], bh[n], acc, 0, 0, 0);
      acc = __builtin_amdgcn_mfma_f32_16x16x32_bf16(ah[g], bl[n], acc, 0, 0, 0);
      acc = __builtin_amdgcn_mfma_f32_16x16x32_bf16(al[g], bh[n], acc, 0, 0, 0);
      int cc = c0 + n * 16 + l15;
#pragma unroll
      for (int j = 0; j < 4; ++j) {
        float v = 1.f / (1.f + __expf(-acc[j]));
        adj[(size_t)(rbase + j) * N_NODES + cc] = v;
      }
    }
  }
}

// ====================================================================================
extern "C" void kernel_launch(void* const* d_in, const int* in_sizes, int n_in,
                              void* d_out, int out_size, void* d_ws, size_t ws_size,
                              hipStream_t stream) {
  const float* x   = (const float*)d_in[0];
  const int*   ei  = (const int*)d_in[1];
  const float* W1  = (const float*)d_in[2];
  const float* as1 = (const float*)d_in[3];
  const float* ad1 = (const float*)d_in[4];
  const float* b1  = (const float*)d_in[5];
  const float* W2  = (const float*)d_in[6];
  const float* as2 = (const float*)d_in[7];
  const float* ad2 = (const float*)d_in[8];
  const float* b2  = (const float*)d_in[9];
  const float* W3  = (const float*)d_in[10];
  const float* as3 = (const float*)d_in[11];
  const float* ad3 = (const float*)d_in[12];
  const float* b3  = (const float*)d_in[13];
  const float* centers = (const float*)d_in[14];
  float* out = (float*)d_out;

  char* ws = (char*)d_ws;
  size_t off = 0;
  auto alloc = [&](size_t bytes) { void* p = ws + off; off = (off + bytes + 255) & ~(size_t)255; return p; };
  int* cnt       = (int*)alloc((size_t)N_NODES * 4);           // cnt+cur contiguous
  int* cur       = (int*)alloc((size_t)N_NODES * 4);
  int* row_ptr   = (int*)alloc((size_t)(N_NODES + 1) * 4);
  int* bsum      = (int*)alloc(64 * 4);
  int* csr_src   = (int*)alloc((size_t)EP_EDGES * 4);
  float* asrcA   = (float*)alloc((size_t)N_NODES * HEADS * 4);
  float* adstA   = (float*)alloc((size_t)N_NODES * HEADS * 4);
  float* asrcP   = (float*)alloc((size_t)N_NODES * 16 * 4);    // per-(row,head,quarter)
  float* adstP   = (float*)alloc((size_t)N_NODES * 16 * 4);
  float* asrcR   = (float*)alloc((size_t)N_NODES * 4 * 4);     // reduced per-(node,head)
  float* adstR   = (float*)alloc((size_t)N_NODES * 4 * 4);
  float* asrc3   = (float*)alloc((size_t)N_NODES * 4);
  float* adst3   = (float*)alloc((size_t)N_NODES * 4);
  float* wa      = (float*)alloc(1024 * 4);
  unsigned short* xbf    = (unsigned short*)alloc((size_t)N_NODES * 128 * 2);
  unsigned short* aggxHi = (unsigned short*)alloc((size_t)N_NODES * 512 * 2);
  unsigned short* h1bf   = (unsigned short*)alloc((size_t)N_NODES * FDIM * 2);
  unsigned short* hbf    = (unsigned short*)alloc((size_t)N_NODES * FDIM * 2);  // h2 bf16
  unsigned int*   h8     = (unsigned int*)alloc((size_t)N_NODES * FDIM);        // h2 fp8
  unsigned short* agg2Hi = (unsigned short*)alloc((size_t)N_NODES * FDIM * 2);
  unsigned short* w1tHi  = (unsigned short*)alloc((size_t)FDIM * 128 * 2);
  unsigned short* w2tHi  = (unsigned short*)alloc((size_t)FDIM * FDIM * 2);
  unsigned short* w3t    = (unsigned short*)alloc((size_t)16 * FDIM * 2);
  unsigned short* zh     = (unsigned short*)alloc((size_t)N_NODES * EMB * 2);
  unsigned short* zl     = (unsigned short*)alloc((size_t)N_NODES * EMB * 2);
  float* bufZ    = (float*)alloc((size_t)N_NODES * EMB * 4);

  hipMemsetAsync(cnt, 0, (size_t)N_NODES * 8, stream);                 // cnt + cur

  // ---- K1: hist ∥ prep (x->bf16, W1t, W2t, wa, W3t)
  k_hist_prep<<<dim3(HIST_BLKS + 1536 + 128 + 1024 + 2), dim3(256), 0, stream>>>(
      ei, cnt, x, xbf, W1, w1tHi, W2, w2tHi, as1, ad1, wa, W3, w3t);

  // ---- K2: scan1 ∥ alpha_x
  k_scan_alpha<<<dim3(12 + 48), dim3(1024), 0, stream>>>(
      cnt, row_ptr, bsum, x, wa, asrcA, adstA);

  // ---- K3/K4: finish scan, scatter
  k_scan23<<<dim3(N_NODES / 256), dim3(256), 0, stream>>>(row_ptr, bsum);
  k_scatter<<<dim3((EP_EDGES + 255) / 256), dim3(256), 0, stream>>>(ei, row_ptr, cur, csr_src);

  // ---- layer 1 (commuted): aggregate x (all heads/wave), project (+bias+ELU)
  k_aggx<<<dim3(N_NODES / 4), dim3(256), 0, stream>>>(xbf, asrcA, adstA, row_ptr, csr_src, aggxHi);
  k_gemm<1><<<dim3(FDIM / 128, N_NODES / 128), dim3(256), 0, stream>>>(
      aggxHi, w1tHi, h1bf, b1, nullptr, nullptr, nullptr, nullptr, N_NODES, FDIM, 128, 512);

  // ---- layer 2: bf16 GEMM + fused alpha partials; repack->fp8 ∥ reduce alphas
  k_gemm<0><<<dim3(FDIM / 128, N_NODES / 128), dim3(256), 0, stream>>>(
      h1bf, w2tHi, hbf, nullptr, as2, ad2, asrcP, adstP, N_NODES, FDIM, FDIM, FDIM);
  k_repack8<<<dim3(12288 + N_NODES * 4 / 256), dim3(256), 0, stream>>>(
      hbf, h8, asrcP, adstP, asrcR, adstR);
  k_agg4<<<dim3(N_NODES / 4), dim3(256), 0, stream>>>(h8, asrcR, adstR, row_ptr, csr_src, b2, agg2Hi);

  // ---- layer 3: MFMA GEMM (alpha fused); agg1 fuses q + z hi/lo
  k_gemm_n16<<<dim3(N_NODES / 64), dim3(256), 0, stream>>>(
      agg2Hi, w3t, as3, ad3, bufZ, asrc3, adst3);
  float* adj = out + (size_t)N_NODES * EMB;
  float* q   = adj + (size_t)N_NODES * N_NODES;
  k_agg1<<<dim3(N_NODES * EMB / 256), dim3(256), 0, stream>>>(
      bufZ, asrc3, adst3, row_ptr, csr_src, b3, centers, out, q, zh, zl);

  // ---- adjacency decoder: MFMA z@z^T
  k_adj<<<dim3(N_NODES / 128, N_NODES / 128), dim3(256), 0, stream>>>(zh, zl, adj);
}

// Round 14
// 378.217 us; speedup vs baseline: 1.3065x; 1.0361x over previous
//
#include <hip/hip_runtime.h>
#include <hip/hip_bf16.h>
#include <math.h>

#define N_NODES 12288
#define N_EDGES 196608
#define EP_EDGES (N_EDGES + N_NODES)   // 208896 edges incl. self loops
#define HEADS 4
#define HID 256
#define FDIM 1024                      // HEADS*HID
#define EMB 16
#define NEG_SLOPE 0.2f

typedef __attribute__((ext_vector_type(8))) short short8;
typedef __attribute__((ext_vector_type(4))) float f32x4;
typedef __attribute__((ext_vector_type(2))) float f32x2;

// bf16 helpers (RNE)
__device__ __forceinline__ unsigned short f2bf(float f) {
  unsigned int u = __float_as_uint(f);
  u = (u + 0x7FFFu + ((u >> 16) & 1u)) >> 16;
  return (unsigned short)u;
}
__device__ __forceinline__ float bf2f(unsigned short h) {
  return __uint_as_float(((unsigned int)h) << 16);
}

// ---------------- K1: hist ∥ x->fp8 ∥ W1t ∥ W2t ∥ wa ∥ W3t --------------------------
__device__ __forceinline__ void t_tile_hi(const float* __restrict__ W,
                                          unsigned short* __restrict__ Th,
                                          int K, int N, int k0, int n0,
                                          int t, float (*tile)[33]) {
  int rr = t >> 3, cc = (t & 7) * 4;
  float4 v = *reinterpret_cast<const float4*>(&W[(size_t)(k0 + rr) * N + n0 + cc]);
  tile[rr][cc + 0] = v.x; tile[rr][cc + 1] = v.y; tile[rr][cc + 2] = v.z; tile[rr][cc + 3] = v.w;
  __syncthreads();
  ushort4 h;
  h.x = f2bf(tile[cc + 0][rr]);
  h.y = f2bf(tile[cc + 1][rr]);
  h.z = f2bf(tile[cc + 2][rr]);
  h.w = f2bf(tile[cc + 3][rr]);
  *reinterpret_cast<ushort4*>(&Th[(size_t)(n0 + rr) * K + k0 + cc]) = h;
}

#define HIST_BLKS (EP_EDGES / 256)     // 816
__global__ __launch_bounds__(256) void k_hist_prep(const int* __restrict__ ei,
                                                   int* __restrict__ cnt,
                                                   const float* __restrict__ x,
                                                   unsigned int* __restrict__ x8,
                                                   const float* __restrict__ W1,
                                                   unsigned short* __restrict__ w1tHi,
                                                   const float* __restrict__ W2,
                                                   unsigned short* __restrict__ w2tHi,
                                                   const float* __restrict__ as1,
                                                   const float* __restrict__ ad1,
                                                   float* __restrict__ wa,
                                                   const float* __restrict__ W3,
                                                   unsigned short* __restrict__ w3t) {
  __shared__ float tile[32][33];
  int b = blockIdx.x, t = threadIdx.x;
  if (b < HIST_BLKS) {
    int i = b * 256 + t;
    if (i < EP_EDGES) {
      int d = (i < N_EDGES) ? ei[N_EDGES + i] : (i - N_EDGES);
      atomicAdd(&cnt[d], 1);
    }
  } else if (b < HIST_BLKS + 1536) {               // x -> fp8 (1 uint = 4 vals/thread)
    int i = (b - HIST_BLKS) * 256 + t;
    float4 v = *reinterpret_cast<const float4*>(&x[(size_t)i * 4]);
    int w = __builtin_amdgcn_cvt_pk_fp8_f32(v.x, v.y, 0, false);
    w = __builtin_amdgcn_cvt_pk_fp8_f32(v.z, v.w, w, true);
    x8[i] = (unsigned int)w;
  } else if (b < HIST_BLKS + 1536 + 128) {         // W1 [128,1024] -> [1024,128] bf16
    int tt = b - HIST_BLKS - 1536;
    t_tile_hi(W1, w1tHi, 128, FDIM, (tt >> 5) * 32, (tt & 31) * 32, t, tile);
  } else if (b < HIST_BLKS + 1536 + 128 + 1024) {  // W2 [1024,1024] -> [1024,1024] bf16
    int tt = b - HIST_BLKS - 1536 - 128;
    t_tile_hi(W2, w2tHi, FDIM, FDIM, (tt >> 5) * 32, (tt & 31) * 32, t, tile);
  } else if (b == HIST_BLKS + 1536 + 128 + 1024) { // wa GEMV
    for (int idx = t; idx < 1024; idx += 256) {
      int sd = idx >> 9, h = (idx >> 7) & 3, k = idx & 127;
      const float* av = sd ? ad1 : as1;
      float acc = 0.f;
      for (int f = 0; f < 256; ++f)
        acc = fmaf(W1[(size_t)k * FDIM + h * 256 + f], av[h * 256 + f], acc);
      wa[idx] = acc;
    }
  } else {                                         // W3 [1024,16] -> w3t [16,1024] bf16
    for (int idx = t; idx < 16384; idx += 256) {
      int c = idx >> 10, k = idx & 1023;
      w3t[idx] = f2bf(W3[(size_t)k * 16 + c]);
    }
  }
}

// ---------------- K2: scan1 (blocks 0-11) ∥ alpha_x (blocks 12-59), 1024 thr --------
__global__ __launch_bounds__(1024) void k_scan_alpha(const int* __restrict__ cnt,
                                                     int* __restrict__ row_ptr,
                                                     int* __restrict__ bsum,
                                                     const float* __restrict__ x,
                                                     const float* __restrict__ wa,
                                                     float* __restrict__ asrc,
                                                     float* __restrict__ adst) {
  __shared__ int sd[1024];
  int tid = threadIdx.x;
  if (blockIdx.x < 12) {                           // exclusive scan of cnt
    int gid = blockIdx.x * 1024 + tid;
    int v = cnt[gid];
    sd[tid] = v;
    __syncthreads();
    for (int d = 1; d < 1024; d <<= 1) {
      int t2 = (tid >= d) ? sd[tid - d] : 0;
      __syncthreads();
      sd[tid] += t2;
      __syncthreads();
    }
    row_ptr[gid] = sd[tid] - v;
    if (tid == 1023) bsum[blockIdx.x] = sd[1023];
  } else {                                         // layer-1 alphas from x
    int id = (blockIdx.x - 12) * 1024 + tid;       // N*4
    int n = id >> 2, h = id & 3;
    const float* wsv = wa + h * 128;
    const float* wdv = wa + 512 + h * 128;
    const float* xr = x + (size_t)n * 128;
    float accs = 0.f, accd = 0.f;
#pragma unroll
    for (int k = 0; k < 128; k += 4) {
      float4 xv = *reinterpret_cast<const float4*>(&xr[k]);
      float4 s4 = *reinterpret_cast<const float4*>(&wsv[k]);
      float4 d4 = *reinterpret_cast<const float4*>(&wdv[k]);
      accs = fmaf(xv.x, s4.x, fmaf(xv.y, s4.y, fmaf(xv.z, s4.z, fmaf(xv.w, s4.w, accs))));
      accd = fmaf(xv.x, d4.x, fmaf(xv.y, d4.y, fmaf(xv.z, d4.z, fmaf(xv.w, d4.w, accd))));
    }
    asrc[n * 4 + h] = accs;
    adst[n * 4 + h] = accd;
  }
}

// ---------------- K3: add block offsets (scan2 inlined per-thread) ------------------
__global__ void k_scan23(int* __restrict__ row_ptr, const int* __restrict__ bsum) {
  int gid = blockIdx.x * 256 + threadIdx.x;
  int blk = gid >> 10;
  int boffv = 0;
  for (int j = 0; j < blk; ++j) boffv += bsum[j];
  row_ptr[gid] += boffv;
  if (gid == 0) {
    int tot = 0;
    for (int j = 0; j < 12; ++j) tot += bsum[j];
    row_ptr[N_NODES] = tot;
  }
}

__global__ void k_scatter(const int* __restrict__ ei, const int* __restrict__ row_ptr,
                          int* __restrict__ cur, int* __restrict__ csr_src) {
  int i = blockIdx.x * 256 + threadIdx.x;
  if (i >= EP_EDGES) return;
  int s, d;
  if (i < N_EDGES) { s = ei[i]; d = ei[N_EDGES + i]; }
  else             { s = i - N_EDGES; d = s; }
  int pos = row_ptr[d] + atomicAdd(&cur[d], 1);
  csr_src[pos] = s;
}

// ---------------- layer-1 aggregation: wave/node, TWO edges/iter (half-waves) --------
// fp8 x; lane (l = lane&31) owns 4 features; half h processes edges beg+h, beg+h+2, ...
__global__ __launch_bounds__(256) void k_aggx(const unsigned int* __restrict__ x8,
                                              const float* __restrict__ asrc,
                                              const float* __restrict__ adst,
                                              const int* __restrict__ row_ptr,
                                              const int* __restrict__ csr_src,
                                              unsigned short* __restrict__ outHi) {
  int node = (blockIdx.x * 256 + threadIdx.x) >> 6;
  int lane = threadIdx.x & 63;
  int half = lane >> 5, l = lane & 31;
  int beg = row_ptr[node], end = row_ptr[node + 1];
  float4 adn = *reinterpret_cast<const float4*>(&adst[node * 4]);
  float m0 = -INFINITY, m1 = -INFINITY, m2 = -INFINITY, m3 = -INFINITY;
  float s0 = 0.f, s1 = 0.f, s2 = 0.f, s3 = 0.f;
  float acc[16];
#pragma unroll
  for (int k = 0; k < 16; ++k) acc[k] = 0.f;
  for (int e = beg + half; e < end; e += 2) {
    int sidx = csr_src[e];
    float4 av = *reinterpret_cast<const float4*>(&asrc[sidx * 4]);
    unsigned int dw = x8[(size_t)sidx * 32 + l];
    f32x2 lo = __builtin_amdgcn_cvt_pk_f32_fp8(dw, false);
    f32x2 hi = __builtin_amdgcn_cvt_pk_f32_fp8(dw, true);
    float a, nm, sc, p;
    a = av.x + adn.x; a = a > 0.f ? a : NEG_SLOPE * a;
    nm = fmaxf(m0, a); sc = __expf(m0 - nm); p = __expf(a - nm); m0 = nm;
    s0 = s0 * sc + p;
    acc[0] = acc[0] * sc + p * lo.x; acc[1] = acc[1] * sc + p * lo.y;
    acc[2] = acc[2] * sc + p * hi.x; acc[3] = acc[3] * sc + p * hi.y;
    a = av.y + adn.y; a = a > 0.f ? a : NEG_SLOPE * a;
    nm = fmaxf(m1, a); sc = __expf(m1 - nm); p = __expf(a - nm); m1 = nm;
    s1 = s1 * sc + p;
    acc[4] = acc[4] * sc + p * lo.x; acc[5] = acc[5] * sc + p * lo.y;
    acc[6] = acc[6] * sc + p * hi.x; acc[7] = acc[7] * sc + p * hi.y;
    a = av.z + adn.z; a = a > 0.f ? a : NEG_SLOPE * a;
    nm = fmaxf(m2, a); sc = __expf(m2 - nm); p = __expf(a - nm); m2 = nm;
    s2 = s2 * sc + p;
    acc[8] = acc[8] * sc + p * lo.x; acc[9] = acc[9] * sc + p * lo.y;
    acc[10] = acc[10] * sc + p * hi.x; acc[11] = acc[11] * sc + p * hi.y;
    a = av.w + adn.w; a = a > 0.f ? a : NEG_SLOPE * a;
    nm = fmaxf(m3, a); sc = __expf(m3 - nm); p = __expf(a - nm); m3 = nm;
    s3 = s3 * sc + p;
    acc[12] = acc[12] * sc + p * lo.x; acc[13] = acc[13] * sc + p * lo.y;
    acc[14] = acc[14] * sc + p * hi.x; acc[15] = acc[15] * sc + p * hi.y;
  }
  // merge the two half-wave states (symmetric; exp(-inf - nm)=0 handles empty half)
  float mm[4] = {m0, m1, m2, m3};
  float ss[4] = {s0, s1, s2, s3};
#pragma unroll
  for (int h = 0; h < 4; ++h) {
    float mo = __shfl_xor(mm[h], 32);
    float so = __shfl_xor(ss[h], 32);
    float nm = fmaxf(mm[h], mo);
    float scS = __expf(mm[h] - nm);
    float scO = __expf(mo - nm);
    ss[h] = ss[h] * scS + so * scO;
#pragma unroll
    for (int k = 0; k < 4; ++k) {
      float ao = __shfl_xor(acc[h * 4 + k], 32);
      acc[h * 4 + k] = acc[h * 4 + k] * scS + ao * scO;
    }
  }
  if (half == 0) {
    size_t base = (size_t)node * 512 + l * 4;
#pragma unroll
    for (int h = 0; h < 4; ++h) {
      float inv = 1.f / ss[h];
      ushort4 o;
      o.x = f2bf(acc[h * 4 + 0] * inv);
      o.y = f2bf(acc[h * 4 + 1] * inv);
      o.z = f2bf(acc[h * 4 + 2] * inv);
      o.w = f2bf(acc[h * 4 + 3] * inv);
      *reinterpret_cast<ushort4*>(&outHi[base + h * 128]) = o;
    }
  }
}

// ---------------- bf16 MFMA GEMM: C[M,N] = A[M,K] @ B[N,K]^T, 128x128, BK=32 ---------
// MODE 1: head-sliced A (lda, aoff), bias+ELU, bf16 out.
// MODE 0: plain bf16 out + NON-ATOMIC per-(row,head,quarter) alpha partials.
template <int MODE>
__global__ __launch_bounds__(256) void k_gemm(const unsigned short* __restrict__ A,
                                              const unsigned short* __restrict__ B,
                                              unsigned short* __restrict__ Out,
                                              const float* __restrict__ bias,
                                              const float* __restrict__ a_s,
                                              const float* __restrict__ a_d,
                                              float* __restrict__ asrcP,
                                              float* __restrict__ adstP,
                                              int M, int N, int K, int lda) {
  __shared__ unsigned short sA[128 * 32], sB[128 * 32];
  const int tid = threadIdx.x;
  const int lane = tid & 63, wv = tid >> 6;
  const int row0 = blockIdx.y * 128, col0 = blockIdx.x * 128;
  const int mBase = (wv >> 1) * 64, nBase = (wv & 1) * 64;
  const int lane15 = lane & 15;
  const int aoff = (MODE == 1) ? (col0 >> 8) * 128 : 0;

  f32x4 acc[4][4];
#pragma unroll
  for (int m = 0; m < 4; ++m)
#pragma unroll
    for (int n = 0; n < 4; ++n) acc[m][n] = (f32x4){0.f, 0.f, 0.f, 0.f};

  int rS[2], cS[2], dS[2];
#pragma unroll
  for (int c = 0; c < 2; ++c) {
    int p = c * 4096 + tid * 16;
    int r = p >> 6, u = (p >> 4) & 3;
    int f = (r & 3) ^ ((r >> 2) & 3);
    rS[c] = r; cS[c] = (u ^ f) * 8; dS[c] = c * 2048 + tid * 8;
  }
  const int fR = (lane & 3) ^ ((lane >> 2) & 3);
  const int uprime = (((lane >> 4) ^ fR) * 8);

  for (int k0 = 0; k0 < K; k0 += 32) {
#pragma unroll
    for (int c = 0; c < 2; ++c) {
      size_t ga = (size_t)(row0 + rS[c]) * lda + aoff + k0 + cS[c];
      size_t gb = (size_t)(col0 + rS[c]) * K + k0 + cS[c];
      __builtin_amdgcn_global_load_lds((const __attribute__((address_space(1))) void*)(A + ga),
                                       (__attribute__((address_space(3))) void*)(sA + dS[c]), 16, 0, 0);
      __builtin_amdgcn_global_load_lds((const __attribute__((address_space(1))) void*)(B + gb),
                                       (__attribute__((address_space(3))) void*)(sB + dS[c]), 16, 0, 0);
    }
    __syncthreads();

    short8 a[4], b[4];
#pragma unroll
    for (int m = 0; m < 4; ++m) {
      int ia = (mBase + m * 16 + lane15) * 32 + uprime;
      a[m] = *reinterpret_cast<const short8*>(sA + ia);
      int ib = (nBase + m * 16 + lane15) * 32 + uprime;
      b[m] = *reinterpret_cast<const short8*>(sB + ib);
    }
#pragma unroll
    for (int m = 0; m < 4; ++m)
#pragma unroll
      for (int n = 0; n < 4; ++n)
        acc[m][n] = __builtin_amdgcn_mfma_f32_16x16x32_bf16(a[m], b[n], acc[m][n], 0, 0, 0);
    __syncthreads();
  }

  const int head = col0 >> 8;
  const int q = ((col0 >> 6) & 2) | (nBase >> 6);
  float asv[4], adv[4];
  if (MODE == 0) {
#pragma unroll
    for (int n = 0; n < 4; ++n) {
      int cc = col0 + nBase + n * 16 + lane15;
      asv[n] = a_s[cc];
      adv[n] = a_d[cc];
    }
  }

  // C/D layout: col = lane&15, row = (lane>>4)*4 + j  [verified m89]
#pragma unroll
  for (int m = 0; m < 4; ++m) {
    int rr = row0 + mBase + m * 16 + (lane >> 4) * 4;
#pragma unroll
    for (int j = 0; j < 4; ++j) {
      if (MODE == 1) {
#pragma unroll
        for (int n = 0; n < 4; ++n) {
          int cc = col0 + nBase + n * 16 + lane15;
          float v = acc[m][n][j] + bias[cc];
          v = v > 0.f ? v : __expf(v) - 1.f;       // ELU
          Out[(size_t)(rr + j) * N + cc] = f2bf(v);
        }
      } else {
        float ps = 0.f, pd = 0.f;
#pragma unroll
        for (int n = 0; n < 4; ++n) {
          int cc = col0 + nBase + n * 16 + lane15;
          float v = acc[m][n][j];
          Out[(size_t)(rr + j) * N + cc] = f2bf(v);
          ps = fmaf(v, asv[n], ps);
          pd = fmaf(v, adv[n], pd);
        }
        ps += __shfl_xor(ps, 1); pd += __shfl_xor(pd, 1);
        ps += __shfl_xor(ps, 2); pd += __shfl_xor(pd, 2);
        ps += __shfl_xor(ps, 4); pd += __shfl_xor(pd, 4);
        ps += __shfl_xor(ps, 8); pd += __shfl_xor(pd, 8);
        if (lane15 == 0) {                          // exactly one writer per slot
          asrcP[(size_t)(rr + j) * 16 + head * 4 + q] = ps;
          adstP[(size_t)(rr + j) * 16 + head * 4 + q] = pd;
        }
      }
    }
  }
}

// ---------------- repack h2 bf16->fp8 ∥ reduce alpha quarters -----------------------
__global__ void k_repack8(const unsigned short* __restrict__ hbf,
                          unsigned int* __restrict__ h8,
                          const float* __restrict__ asrcP,
                          const float* __restrict__ adstP,
                          float* __restrict__ asrcR,
                          float* __restrict__ adstR) {
  int b = blockIdx.x;
  if (b < 12288) {                                 // N*FDIM/4/256
    int i = b * 256 + threadIdx.x;                 // one output dword = 4 fp8
    ushort4 v = *reinterpret_cast<const ushort4*>(&hbf[(size_t)i * 4]);
    int w = __builtin_amdgcn_cvt_pk_fp8_f32(bf2f(v.x), bf2f(v.y), 0, false);
    w = __builtin_amdgcn_cvt_pk_fp8_f32(bf2f(v.z), bf2f(v.w), w, true);
    h8[i] = (unsigned int)w;
  } else {                                         // reduce quarters: N*4 scalars
    int i = (b - 12288) * 256 + threadIdx.x;
    float4 sq = *reinterpret_cast<const float4*>(&asrcP[(size_t)i * 4]);
    asrcR[i] = sq.x + sq.y + sq.z + sq.w;
    float4 dq = *reinterpret_cast<const float4*>(&adstP[(size_t)i * 4]);
    adstR[i] = dq.x + dq.y + dq.z + dq.w;
  }
}

// ---------------- GAT aggregation of fp8 h2: ONE wave per node, 16 feat/lane ---------
__global__ __launch_bounds__(256) void k_agg4(const unsigned int* __restrict__ h8,
                                              const float* __restrict__ asrcR,
                                              const float* __restrict__ adstR,
                                              const int* __restrict__ row_ptr,
                                              const int* __restrict__ csr_src, const float* __restrict__ bias,
                                              unsigned short* __restrict__ outHi) {
  int node = (blockIdx.x * 256 + threadIdx.x) >> 6;
  int lane = threadIdx.x & 63;
  int hd = lane >> 4;
  int beg = row_ptr[node], end = row_ptr[node + 1];
  float adn = adstR[node * 4 + hd];
  float m = -INFINITY, s = 0.f;
  float acc[16];
#pragma unroll
  for (int k = 0; k < 16; ++k) acc[k] = 0.f;
  for (int e = beg; e < end; ++e) {
    int sidx = csr_src[e];
    float a = asrcR[sidx * 4 + hd] + adn;
    a = a > 0.f ? a : NEG_SLOPE * a;            // leaky_relu
    float nm = fmaxf(m, a);
    float sc = __expf(m - nm);                  // exp(-inf)=0 on first edge
    float p  = __expf(a - nm);
    m = nm;
    s = s * sc + p;
    uint4 dw = *reinterpret_cast<const uint4*>(h8 + (size_t)sidx * 256 + lane * 4);
#pragma unroll
    for (int d = 0; d < 4; ++d) {
      unsigned int w = (&dw.x)[d];
      f32x2 lo = __builtin_amdgcn_cvt_pk_f32_fp8(w, false);
      f32x2 hi = __builtin_amdgcn_cvt_pk_f32_fp8(w, true);
      acc[d * 4 + 0] = acc[d * 4 + 0] * sc + p * lo.x;
      acc[d * 4 + 1] = acc[d * 4 + 1] * sc + p * lo.y;
      acc[d * 4 + 2] = acc[d * 4 + 2] * sc + p * hi.x;
      acc[d * 4 + 3] = acc[d * 4 + 3] * sc + p * hi.y;
    }
  }
  float inv = 1.f / s;
  int fo = lane * 16;
#pragma unroll
  for (int d = 0; d < 4; ++d) {
    float4 bv = *reinterpret_cast<const float4*>(&bias[fo + d * 4]);
    float v0 = acc[d * 4 + 0] * inv + bv.x;
    float v1 = acc[d * 4 + 1] * inv + bv.y;
    float v2 = acc[d * 4 + 2] * inv + bv.z;
    float v3 = acc[d * 4 + 3] * inv + bv.w;
    v0 = v0 > 0.f ? v0 : __expf(v0) - 1.f;       // ELU
    v1 = v1 > 0.f ? v1 : __expf(v1) - 1.f;
    v2 = v2 > 0.f ? v2 : __expf(v2) - 1.f;
    v3 = v3 > 0.f ? v3 : __expf(v3) - 1.f;
    ushort4 st;
    st.x = f2bf(v0); st.y = f2bf(v1); st.z = f2bf(v2); st.w = f2bf(v3);
    *reinterpret_cast<ushort4*>(&outHi[(size_t)node * FDIM + fo + d * 4]) = st;
  }
}

// ---------------- layer-3 MFMA GEMM: [N,1024](bf16) @ w3t[16,1024]^T + alpha3 --------
__global__ __launch_bounds__(256) void k_gemm_n16(const unsigned short* __restrict__ A,
                                                  const unsigned short* __restrict__ w3t,
                                                  const float* __restrict__ a_s,
                                                  const float* __restrict__ a_d,
                                                  float* __restrict__ C,
                                                  float* __restrict__ asrc,
                                                  float* __restrict__ adst) {
  int wave = (blockIdx.x * 256 + threadIdx.x) >> 6;   // 0..767
  int lane = threadIdx.x & 63;
  int lane15 = lane & 15;
  int row0 = wave * 16;
  int kg = (lane >> 4) * 8;
  f32x4 acc = (f32x4){0.f, 0.f, 0.f, 0.f};
  const unsigned short* Ar = A + (size_t)(row0 + lane15) * FDIM + kg;
  const unsigned short* Br = w3t + (size_t)lane15 * FDIM + kg;
  for (int k0 = 0; k0 < FDIM; k0 += 32) {
    short8 a = *reinterpret_cast<const short8*>(Ar + k0);
    short8 b = *reinterpret_cast<const short8*>(Br + k0);
    acc = __builtin_amdgcn_mfma_f32_16x16x32_bf16(a, b, acc, 0, 0, 0);
  }
  float asv = a_s[lane15], adv = a_d[lane15];
  int rbase = row0 + (lane >> 4) * 4;
#pragma unroll
  for (int j = 0; j < 4; ++j) {
    float v = acc[j];
    C[(size_t)(rbase + j) * EMB + lane15] = v;
    float ps = v * asv, pd = v * adv;
    ps += __shfl_xor(ps, 1); pd += __shfl_xor(pd, 1);
    ps += __shfl_xor(ps, 2); pd += __shfl_xor(pd, 2);
    ps += __shfl_xor(ps, 4); pd += __shfl_xor(pd, 4);
    ps += __shfl_xor(ps, 8); pd += __shfl_xor(pd, 8);
    if (lane15 == 0) { asrc[rbase + j] = ps; adst[rbase + j] = pd; }
  }
}

// layer-3 aggregation (16 threads/node, online) + fused q + z hi/lo bf16 -------------
__global__ __launch_bounds__(256) void k_agg1(const float* __restrict__ h3, const float* __restrict__ asrc,
                                              const float* __restrict__ adst, const int* __restrict__ row_ptr,
                                              const int* __restrict__ csr_src, const float* __restrict__ bias,
                                              const float* __restrict__ centers,
                                              float* __restrict__ z, float* __restrict__ qout,
                                              unsigned short* __restrict__ zh,
                                              unsigned short* __restrict__ zl) {
  int idx = blockIdx.x * 256 + threadIdx.x;
  int node = idx >> 4, f = idx & 15;
  if (node >= N_NODES) return;
  int beg = row_ptr[node], end = row_ptr[node + 1];
  float adn = adst[node];
  float m = -INFINITY, s = 0.f, acc = 0.f;
  for (int e = beg; e < end; ++e) {
    int sidx = csr_src[e];
    float a = asrc[sidx] + adn;
    a = a > 0.f ? a : NEG_SLOPE * a;
    float nm = fmaxf(m, a);
    float sc = __expf(m - nm);
    float p  = __expf(a - nm);
    m = nm;
    s = s * sc + p;
    acc = acc * sc + p * h3[sidx * EMB + f];
  }
  float zv = acc / s + bias[f];
  z[node * EMB + f] = zv;
  unsigned short hv = f2bf(zv);
  zh[node * EMB + f] = hv;
  zl[node * EMB + f] = f2bf(zv - bf2f(hv));
  float d0 = zv - centers[f];       d0 *= d0;
  float d1 = zv - centers[EMB + f]; d1 *= d1;
  d0 += __shfl_xor(d0, 1); d1 += __shfl_xor(d1, 1);
  d0 += __shfl_xor(d0, 2); d1 += __shfl_xor(d1, 2);
  d0 += __shfl_xor(d0, 4); d1 += __shfl_xor(d1, 4);
  d0 += __shfl_xor(d0, 8); d1 += __shfl_xor(d1, 8);
  if (f == 0) {
    float q0 = 1.f / (1.f + d0), q1 = 1.f / (1.f + d1);
    float inv = 1.f / (q0 + q1);
    qout[node * 2 + 0] = q0 * inv;
    qout[node * 2 + 1] = q1 * inv;
  }
}

// ---------------- adjacency: sigmoid(z @ z^T) via MFMA, hi/lo 3-term -----------------
__global__ __launch_bounds__(256) void k_adj(const unsigned short* __restrict__ zh,
                                             const unsigned short* __restrict__ zl,
                                             float* __restrict__ adj) {
  int tid = threadIdx.x;
  int lane = tid & 63, wv = tid >> 6;
  int r0 = blockIdx.y * 128 + wv * 32, c0 = blockIdx.x * 128;
  int l15 = lane & 15, kg = lane >> 4;
  short8 zero = (short8){0, 0, 0, 0, 0, 0, 0, 0};
  short8 ah[2], al[2];
#pragma unroll
  for (int g = 0; g < 2; ++g) {
    int row = r0 + g * 16 + l15;
    if (kg < 2) {
      ah[g] = *reinterpret_cast<const short8*>(&zh[(size_t)row * EMB + kg * 8]);
      al[g] = *reinterpret_cast<const short8*>(&zl[(size_t)row * EMB + kg * 8]);
    } else { ah[g] = zero; al[g] = zero; }
  }
  short8 bh[8], bl[8];
#pragma unroll
  for (int n = 0; n < 8; ++n) {
    int col = c0 + n * 16 + l15;
    if (kg < 2) {
      bh[n] = *reinterpret_cast<const short8*>(&zh[(size_t)col * EMB + kg * 8]);
      bl[n] = *reinterpret_cast<const short8*>(&zl[(size_t)col * EMB + kg * 8]);
    } else { bh[n] = zero; bl[n] = zero; }
  }
#pragma unroll
  for (int g = 0; g < 2; ++g) {
    int rbase = r0 + g * 16 + kg * 4;
#pragma unroll
    for (int n = 0; n < 8; ++n) {
      f32x4 acc = (f32x4){0.f, 0.f, 0.f, 0.f};
      acc = __builtin_amdgcn_mfma_f32_16x16x32_bf16(ah[g], bh[n], acc, 0, 0, 0);
      acc = __builtin_amdgcn_mfma_f32_16x16x32_bf16(ah[g], bl[n], acc, 0, 0, 0);
      acc = __builtin_amdgcn_mfma_f32_16x16x32_bf16(al[g], bh[n], acc, 0, 0, 0);
      int cc = c0 + n * 16 + l15;
#pragma unroll
      for (int j = 0; j < 4; ++j) {
        float v = 1.f / (1.f + __expf(-acc[j]));
        adj[(size_t)(rbase + j) * N_NODES + cc] = v;
      }
    }
  }
}

// ====================================================================================
extern "C" void kernel_launch(void* const* d_in, const int* in_sizes, int n_in,
                              void* d_out, int out_size, void* d_ws, size_t ws_size,
                              hipStream_t stream) {
  const float* x   = (const float*)d_in[0];
  const int*   ei  = (const int*)d_in[1];
  const float* W1  = (const float*)d_in[2];
  const float* as1 = (const float*)d_in[3];
  const float* ad1 = (const float*)d_in[4];
  const float* b1  = (const float*)d_in[5];
  const float* W2  = (const float*)d_in[6];
  const float* as2 = (const float*)d_in[7];
  const float* ad2 = (const float*)d_in[8];
  const float* b2  = (const float*)d_in[9];
  const float* W3  = (const float*)d_in[10];
  const float* as3 = (const float*)d_in[11];
  const float* ad3 = (const float*)d_in[12];
  const float* b3  = (const float*)d_in[13];
  const float* centers = (const float*)d_in[14];
  float* out = (float*)d_out;

  char* ws = (char*)d_ws;
  size_t off = 0;
  auto alloc = [&](size_t bytes) { void* p = ws + off; off = (off + bytes + 255) & ~(size_t)255; return p; };
  int* cnt       = (int*)alloc((size_t)N_NODES * 4);           // cnt+cur contiguous
  int* cur       = (int*)alloc((size_t)N_NODES * 4);
  int* row_ptr   = (int*)alloc((size_t)(N_NODES + 1) * 4);
  int* bsum      = (int*)alloc(64 * 4);
  int* csr_src   = (int*)alloc((size_t)EP_EDGES * 4);
  float* asrcA   = (float*)alloc((size_t)N_NODES * HEADS * 4);
  float* adstA   = (float*)alloc((size_t)N_NODES * HEADS * 4);
  float* asrcP   = (float*)alloc((size_t)N_NODES * 16 * 4);    // per-(row,head,quarter)
  float* adstP   = (float*)alloc((size_t)N_NODES * 16 * 4);
  float* asrcR   = (float*)alloc((size_t)N_NODES * 4 * 4);     // reduced per-(node,head)
  float* adstR   = (float*)alloc((size_t)N_NODES * 4 * 4);
  float* asrc3   = (float*)alloc((size_t)N_NODES * 4);
  float* adst3   = (float*)alloc((size_t)N_NODES * 4);
  float* wa      = (float*)alloc(1024 * 4);
  unsigned int*   x8     = (unsigned int*)alloc((size_t)N_NODES * 128);         // x fp8
  unsigned short* aggxHi = (unsigned short*)alloc((size_t)N_NODES * 512 * 2);
  unsigned short* h1bf   = (unsigned short*)alloc((size_t)N_NODES * FDIM * 2);
  unsigned short* hbf    = (unsigned short*)alloc((size_t)N_NODES * FDIM * 2);  // h2 bf16
  unsigned int*   h8     = (unsigned int*)alloc((size_t)N_NODES * FDIM);        // h2 fp8
  unsigned short* agg2Hi = (unsigned short*)alloc((size_t)N_NODES * FDIM * 2);
  unsigned short* w1tHi  = (unsigned short*)alloc((size_t)FDIM * 128 * 2);
  unsigned short* w2tHi  = (unsigned short*)alloc((size_t)FDIM * FDIM * 2);
  unsigned short* w3t    = (unsigned short*)alloc((size_t)16 * FDIM * 2);
  unsigned short* zh     = (unsigned short*)alloc((size_t)N_NODES * EMB * 2);
  unsigned short* zl     = (unsigned short*)alloc((size_t)N_NODES * EMB * 2);
  float* bufZ    = (float*)alloc((size_t)N_NODES * EMB * 4);

  hipMemsetAsync(cnt, 0, (size_t)N_NODES * 8, stream);                 // cnt + cur

  // ---- K1: hist ∥ prep (x->fp8, W1t, W2t, wa, W3t)
  k_hist_prep<<<dim3(HIST_BLKS + 1536 + 128 + 1024 + 2), dim3(256), 0, stream>>>(
      ei, cnt, x, x8, W1, w1tHi, W2, w2tHi, as1, ad1, wa, W3, w3t);

  // ---- K2: scan1 ∥ alpha_x
  k_scan_alpha<<<dim3(12 + 48), dim3(1024), 0, stream>>>(
      cnt, row_ptr, bsum, x, wa, asrcA, adstA);

  // ---- K3/K4: finish scan, scatter
  k_scan23<<<dim3(N_NODES / 256), dim3(256), 0, stream>>>(row_ptr, bsum);
  k_scatter<<<dim3((EP_EDGES + 255) / 256), dim3(256), 0, stream>>>(ei, row_ptr, cur, csr_src);

  // ---- layer 1 (commuted): aggregate x (2 edges/iter), project (+bias+ELU)
  k_aggx<<<dim3(N_NODES / 4), dim3(256), 0, stream>>>(x8, asrcA, adstA, row_ptr, csr_src, aggxHi);
  k_gemm<1><<<dim3(FDIM / 128, N_NODES / 128), dim3(256), 0, stream>>>(
      aggxHi, w1tHi, h1bf, b1, nullptr, nullptr, nullptr, nullptr, N_NODES, FDIM, 128, 512);

  // ---- layer 2: bf16 GEMM + fused alpha partials; repack->fp8 ∥ reduce alphas
  k_gemm<0><<<dim3(FDIM / 128, N_NODES / 128), dim3(256), 0, stream>>>(
      h1bf, w2tHi, hbf, nullptr, as2, ad2, asrcP, adstP, N_NODES, FDIM, FDIM, FDIM);
  k_repack8<<<dim3(12288 + N_NODES * 4 / 256), dim3(256), 0, stream>>>(
      hbf, h8, asrcP, adstP, asrcR, adstR);
  k_agg4<<<dim3(N_NODES / 4), dim3(256), 0, stream>>>(h8, asrcR, adstR, row_ptr, csr_src, b2, agg2Hi);

  // ---- layer 3: MFMA GEMM (alpha fused); agg1 fuses q + z hi/lo
  k_gemm_n16<<<dim3(N_NODES / 64), dim3(256), 0, stream>>>(
      agg2Hi, w3t, as3, ad3, bufZ, asrc3, adst3);
  float* adj = out + (size_t)N_NODES * EMB;
  float* q   = adj + (size_t)N_NODES * N_NODES;
  k_agg1<<<dim3(N_NODES * EMB / 256), dim3(256), 0, stream>>>(
      bufZ, asrc3, adst3, row_ptr, csr_src, b3, centers, out, q, zh, zl);

  // ---- adjacency decoder: MFMA z@z^T
  k_adj<<<dim3(N_NODES / 128, N_NODES / 128), dim3(256), 0, stream>>>(zh, zl, adj);
}

// Round 15
// 372.942 us; speedup vs baseline: 1.3249x; 1.0141x over previous
//
#include <hip/hip_runtime.h>
#include <hip/hip_bf16.h>
#include <math.h>

#define N_NODES 12288
#define N_EDGES 196608
#define EP_EDGES (N_EDGES + N_NODES)   // 208896 edges incl. self loops
#define HEADS 4
#define HID 256
#define FDIM 1024                      // HEADS*HID
#define EMB 16
#define NEG_SLOPE 0.2f

typedef __attribute__((ext_vector_type(8))) short short8;
typedef __attribute__((ext_vector_type(4))) float f32x4;
typedef __attribute__((ext_vector_type(2))) float f32x2;

// bf16 helpers (RNE)
__device__ __forceinline__ unsigned short f2bf(float f) {
  unsigned int u = __float_as_uint(f);
  u = (u + 0x7FFFu + ((u >> 16) & 1u)) >> 16;
  return (unsigned short)u;
}
__device__ __forceinline__ float bf2f(unsigned short h) {
  return __uint_as_float(((unsigned int)h) << 16);
}

// ---------------- K1: hist ∥ x->fp8 ∥ W1t ∥ W2t ∥ wa ∥ W3t --------------------------
__device__ __forceinline__ void t_tile_hi(const float* __restrict__ W,
                                          unsigned short* __restrict__ Th,
                                          int K, int N, int k0, int n0,
                                          int t, float (*tile)[33]) {
  int rr = t >> 3, cc = (t & 7) * 4;
  float4 v = *reinterpret_cast<const float4*>(&W[(size_t)(k0 + rr) * N + n0 + cc]);
  tile[rr][cc + 0] = v.x; tile[rr][cc + 1] = v.y; tile[rr][cc + 2] = v.z; tile[rr][cc + 3] = v.w;
  __syncthreads();
  ushort4 h;
  h.x = f2bf(tile[cc + 0][rr]);
  h.y = f2bf(tile[cc + 1][rr]);
  h.z = f2bf(tile[cc + 2][rr]);
  h.w = f2bf(tile[cc + 3][rr]);
  *reinterpret_cast<ushort4*>(&Th[(size_t)(n0 + rr) * K + k0 + cc]) = h;
}

#define HIST_BLKS (EP_EDGES / 256)     // 816
__global__ __launch_bounds__(256) void k_hist_prep(const int* __restrict__ ei,
                                                   int* __restrict__ cnt,
                                                   const float* __restrict__ x,
                                                   unsigned int* __restrict__ x8,
                                                   const float* __restrict__ W1,
                                                   unsigned short* __restrict__ w1tHi,
                                                   const float* __restrict__ W2,
                                                   unsigned short* __restrict__ w2tHi,
                                                   const float* __restrict__ as1,
                                                   const float* __restrict__ ad1,
                                                   float* __restrict__ wa,
                                                   const float* __restrict__ W3,
                                                   unsigned short* __restrict__ w3t) {
  __shared__ float tile[32][33];
  int b = blockIdx.x, t = threadIdx.x;
  if (b < HIST_BLKS) {
    int i = b * 256 + t;
    if (i < EP_EDGES) {
      int d = (i < N_EDGES) ? ei[N_EDGES + i] : (i - N_EDGES);
      atomicAdd(&cnt[d], 1);
    }
  } else if (b < HIST_BLKS + 1536) {               // x -> fp8 (1 uint = 4 vals/thread)
    int i = (b - HIST_BLKS) * 256 + t;
    float4 v = *reinterpret_cast<const float4*>(&x[(size_t)i * 4]);
    int w = __builtin_amdgcn_cvt_pk_fp8_f32(v.x, v.y, 0, false);
    w = __builtin_amdgcn_cvt_pk_fp8_f32(v.z, v.w, w, true);
    x8[i] = (unsigned int)w;
  } else if (b < HIST_BLKS + 1536 + 128) {         // W1 [128,1024] -> [1024,128] bf16
    int tt = b - HIST_BLKS - 1536;
    t_tile_hi(W1, w1tHi, 128, FDIM, (tt >> 5) * 32, (tt & 31) * 32, t, tile);
  } else if (b < HIST_BLKS + 1536 + 128 + 1024) {  // W2 [1024,1024] -> [1024,1024] bf16
    int tt = b - HIST_BLKS - 1536 - 128;
    t_tile_hi(W2, w2tHi, FDIM, FDIM, (tt >> 5) * 32, (tt & 31) * 32, t, tile);
  } else if (b == HIST_BLKS + 1536 + 128 + 1024) { // wa GEMV
    for (int idx = t; idx < 1024; idx += 256) {
      int sd = idx >> 9, h = (idx >> 7) & 3, k = idx & 127;
      const float* av = sd ? ad1 : as1;
      float acc = 0.f;
      for (int f = 0; f < 256; ++f)
        acc = fmaf(W1[(size_t)k * FDIM + h * 256 + f], av[h * 256 + f], acc);
      wa[idx] = acc;
    }
  } else {                                         // W3 [1024,16] -> w3t [16,1024] bf16
    for (int idx = t; idx < 16384; idx += 256) {
      int c = idx >> 10, k = idx & 1023;
      w3t[idx] = f2bf(W3[(size_t)k * 16 + c]);
    }
  }
}

// ---------------- K2: scan1 (blocks 0-11) ∥ alpha_x (blocks 12-59), 1024 thr --------
__global__ __launch_bounds__(1024) void k_scan_alpha(const int* __restrict__ cnt,
                                                     int* __restrict__ row_ptr,
                                                     int* __restrict__ bsum,
                                                     const float* __restrict__ x,
                                                     const float* __restrict__ wa,
                                                     float* __restrict__ asrc,
                                                     float* __restrict__ adst) {
  __shared__ int sd[1024];
  int tid = threadIdx.x;
  if (blockIdx.x < 12) {                           // exclusive scan of cnt
    int gid = blockIdx.x * 1024 + tid;
    int v = cnt[gid];
    sd[tid] = v;
    __syncthreads();
    for (int d = 1; d < 1024; d <<= 1) {
      int t2 = (tid >= d) ? sd[tid - d] : 0;
      __syncthreads();
      sd[tid] += t2;
      __syncthreads();
    }
    row_ptr[gid] = sd[tid] - v;
    if (tid == 1023) bsum[blockIdx.x] = sd[1023];
  } else {                                         // layer-1 alphas from x
    int id = (blockIdx.x - 12) * 1024 + tid;       // N*4
    int n = id >> 2, h = id & 3;
    const float* wsv = wa + h * 128;
    const float* wdv = wa + 512 + h * 128;
    const float* xr = x + (size_t)n * 128;
    float accs = 0.f, accd = 0.f;
#pragma unroll
    for (int k = 0; k < 128; k += 4) {
      float4 xv = *reinterpret_cast<const float4*>(&xr[k]);
      float4 s4 = *reinterpret_cast<const float4*>(&wsv[k]);
      float4 d4 = *reinterpret_cast<const float4*>(&wdv[k]);
      accs = fmaf(xv.x, s4.x, fmaf(xv.y, s4.y, fmaf(xv.z, s4.z, fmaf(xv.w, s4.w, accs))));
      accd = fmaf(xv.x, d4.x, fmaf(xv.y, d4.y, fmaf(xv.z, d4.z, fmaf(xv.w, d4.w, accd))));
    }
    asrc[n * 4 + h] = accs;
    adst[n * 4 + h] = accd;
  }
}

// ---------------- K3: add block offsets (scan2 inlined per-thread) ------------------
__global__ void k_scan23(int* __restrict__ row_ptr, const int* __restrict__ bsum) {
  int gid = blockIdx.x * 256 + threadIdx.x;
  int blk = gid >> 10;
  int boffv = 0;
  for (int j = 0; j < blk; ++j) boffv += bsum[j];
  row_ptr[gid] += boffv;
  if (gid == 0) {
    int tot = 0;
    for (int j = 0; j < 12; ++j) tot += bsum[j];
    row_ptr[N_NODES] = tot;
  }
}

__global__ void k_scatter(const int* __restrict__ ei, const int* __restrict__ row_ptr,
                          int* __restrict__ cur, int* __restrict__ csr_src) {
  int i = blockIdx.x * 256 + threadIdx.x;
  if (i >= EP_EDGES) return;
  int s, d;
  if (i < N_EDGES) { s = ei[i]; d = ei[N_EDGES + i]; }
  else             { s = i - N_EDGES; d = s; }
  int pos = row_ptr[d] + atomicAdd(&cur[d], 1);
  csr_src[pos] = s;
}

// ---------------- layer-1 aggregation: wave/node, TWO edges/iter (half-waves) --------
__global__ __launch_bounds__(256) void k_aggx(const unsigned int* __restrict__ x8,
                                              const float* __restrict__ asrc,
                                              const float* __restrict__ adst,
                                              const int* __restrict__ row_ptr,
                                              const int* __restrict__ csr_src,
                                              unsigned short* __restrict__ outHi) {
  int node = (blockIdx.x * 256 + threadIdx.x) >> 6;
  int lane = threadIdx.x & 63;
  int half = lane >> 5, l = lane & 31;
  int beg = row_ptr[node], end = row_ptr[node + 1];
  float4 adn = *reinterpret_cast<const float4*>(&adst[node * 4]);
  float m0 = -INFINITY, m1 = -INFINITY, m2 = -INFINITY, m3 = -INFINITY;
  float s0 = 0.f, s1 = 0.f, s2 = 0.f, s3 = 0.f;
  float acc[16];
#pragma unroll
  for (int k = 0; k < 16; ++k) acc[k] = 0.f;
  for (int e = beg + half; e < end; e += 2) {
    int sidx = csr_src[e];
    float4 av = *reinterpret_cast<const float4*>(&asrc[sidx * 4]);
    unsigned int dw = x8[(size_t)sidx * 32 + l];
    f32x2 lo = __builtin_amdgcn_cvt_pk_f32_fp8(dw, false);
    f32x2 hi = __builtin_amdgcn_cvt_pk_f32_fp8(dw, true);
    float a, nm, sc, p;
    a = av.x + adn.x; a = a > 0.f ? a : NEG_SLOPE * a;
    nm = fmaxf(m0, a); sc = __expf(m0 - nm); p = __expf(a - nm); m0 = nm;
    s0 = s0 * sc + p;
    acc[0] = acc[0] * sc + p * lo.x; acc[1] = acc[1] * sc + p * lo.y;
    acc[2] = acc[2] * sc + p * hi.x; acc[3] = acc[3] * sc + p * hi.y;
    a = av.y + adn.y; a = a > 0.f ? a : NEG_SLOPE * a;
    nm = fmaxf(m1, a); sc = __expf(m1 - nm); p = __expf(a - nm); m1 = nm;
    s1 = s1 * sc + p;
    acc[4] = acc[4] * sc + p * lo.x; acc[5] = acc[5] * sc + p * lo.y;
    acc[6] = acc[6] * sc + p * hi.x; acc[7] = acc[7] * sc + p * hi.y;
    a = av.z + adn.z; a = a > 0.f ? a : NEG_SLOPE * a;
    nm = fmaxf(m2, a); sc = __expf(m2 - nm); p = __expf(a - nm); m2 = nm;
    s2 = s2 * sc + p;
    acc[8] = acc[8] * sc + p * lo.x; acc[9] = acc[9] * sc + p * lo.y;
    acc[10] = acc[10] * sc + p * hi.x; acc[11] = acc[11] * sc + p * hi.y;
    a = av.w + adn.w; a = a > 0.f ? a : NEG_SLOPE * a;
    nm = fmaxf(m3, a); sc = __expf(m3 - nm); p = __expf(a - nm); m3 = nm;
    s3 = s3 * sc + p;
    acc[12] = acc[12] * sc + p * lo.x; acc[13] = acc[13] * sc + p * lo.y;
    acc[14] = acc[14] * sc + p * hi.x; acc[15] = acc[15] * sc + p * hi.y;
  }
  // merge the two half-wave states (symmetric; exp(-inf - nm)=0 handles empty half)
  float mm[4] = {m0, m1, m2, m3};
  float ss[4] = {s0, s1, s2, s3};
#pragma unroll
  for (int h = 0; h < 4; ++h) {
    float mo = __shfl_xor(mm[h], 32);
    float so = __shfl_xor(ss[h], 32);
    float nm = fmaxf(mm[h], mo);
    float scS = __expf(mm[h] - nm);
    float scO = __expf(mo - nm);
    ss[h] = ss[h] * scS + so * scO;
#pragma unroll
    for (int k = 0; k < 4; ++k) {
      float ao = __shfl_xor(acc[h * 4 + k], 32);
      acc[h * 4 + k] = acc[h * 4 + k] * scS + ao * scO;
    }
  }
  if (half == 0) {
    size_t base = (size_t)node * 512 + l * 4;
#pragma unroll
    for (int h = 0; h < 4; ++h) {
      float inv = 1.f / ss[h];
      ushort4 o;
      o.x = f2bf(acc[h * 4 + 0] * inv);
      o.y = f2bf(acc[h * 4 + 1] * inv);
      o.z = f2bf(acc[h * 4 + 2] * inv);
      o.w = f2bf(acc[h * 4 + 3] * inv);
      *reinterpret_cast<ushort4*>(&outHi[base + h * 128]) = o;
    }
  }
}

// ---------------- bf16 MFMA GEMM: C[M,N] = A[M,K] @ B[N,K]^T, 128x128, BK=32 ---------
// MODE 1: head-sliced A (lda, aoff), bias+ELU, bf16 out.
// MODE 0: plain bf16 out + NON-ATOMIC per-(row,head,quarter) alpha partials.
template <int MODE>
__global__ __launch_bounds__(256) void k_gemm(const unsigned short* __restrict__ A,
                                              const unsigned short* __restrict__ B,
                                              unsigned short* __restrict__ Out,
                                              const float* __restrict__ bias,
                                              const float* __restrict__ a_s,
                                              const float* __restrict__ a_d,
                                              float* __restrict__ asrcP,
                                              float* __restrict__ adstP,
                                              int M, int N, int K, int lda) {
  __shared__ unsigned short sA[128 * 32], sB[128 * 32];
  const int tid = threadIdx.x;
  const int lane = tid & 63, wv = tid >> 6;
  const int row0 = blockIdx.y * 128, col0 = blockIdx.x * 128;
  const int mBase = (wv >> 1) * 64, nBase = (wv & 1) * 64;
  const int lane15 = lane & 15;
  const int aoff = (MODE == 1) ? (col0 >> 8) * 128 : 0;

  f32x4 acc[4][4];
#pragma unroll
  for (int m = 0; m < 4; ++m)
#pragma unroll
    for (int n = 0; n < 4; ++n) acc[m][n] = (f32x4){0.f, 0.f, 0.f, 0.f};

  int rS[2], cS[2], dS[2];
#pragma unroll
  for (int c = 0; c < 2; ++c) {
    int p = c * 4096 + tid * 16;
    int r = p >> 6, u = (p >> 4) & 3;
    int f = (r & 3) ^ ((r >> 2) & 3);
    rS[c] = r; cS[c] = (u ^ f) * 8; dS[c] = c * 2048 + tid * 8;
  }
  const int fR = (lane & 3) ^ ((lane >> 2) & 3);
  const int uprime = (((lane >> 4) ^ fR) * 8);

  for (int k0 = 0; k0 < K; k0 += 32) {
#pragma unroll
    for (int c = 0; c < 2; ++c) {
      size_t ga = (size_t)(row0 + rS[c]) * lda + aoff + k0 + cS[c];
      size_t gb = (size_t)(col0 + rS[c]) * K + k0 + cS[c];
      __builtin_amdgcn_global_load_lds((const __attribute__((address_space(1))) void*)(A + ga),
                                       (__attribute__((address_space(3))) void*)(sA + dS[c]), 16, 0, 0);
      __builtin_amdgcn_global_load_lds((const __attribute__((address_space(1))) void*)(B + gb),
                                       (__attribute__((address_space(3))) void*)(sB + dS[c]), 16, 0, 0);
    }
    __syncthreads();

    short8 a[4], b[4];
#pragma unroll
    for (int m = 0; m < 4; ++m) {
      int ia = (mBase + m * 16 + lane15) * 32 + uprime;
      a[m] = *reinterpret_cast<const short8*>(sA + ia);
      int ib = (nBase + m * 16 + lane15) * 32 + uprime;
      b[m] = *reinterpret_cast<const short8*>(sB + ib);
    }
#pragma unroll
    for (int m = 0; m < 4; ++m)
#pragma unroll
      for (int n = 0; n < 4; ++n)
        acc[m][n] = __builtin_amdgcn_mfma_f32_16x16x32_bf16(a[m], b[n], acc[m][n], 0, 0, 0);
    __syncthreads();
  }

  const int head = col0 >> 8;
  const int q = ((col0 >> 6) & 2) | (nBase >> 6);
  float asv[4], adv[4];
  if (MODE == 0) {
#pragma unroll
    for (int n = 0; n < 4; ++n) {
      int cc = col0 + nBase + n * 16 + lane15;
      asv[n] = a_s[cc];
      adv[n] = a_d[cc];
    }
  }

  // C/D layout: col = lane&15, row = (lane>>4)*4 + j  [verified m89]
#pragma unroll
  for (int m = 0; m < 4; ++m) {
    int rr = row0 + mBase + m * 16 + (lane >> 4) * 4;
#pragma unroll
    for (int j = 0; j < 4; ++j) {
      if (MODE == 1) {
#pragma unroll
        for (int n = 0; n < 4; ++n) {
          int cc = col0 + nBase + n * 16 + lane15;
          float v = acc[m][n][j] + bias[cc];
          v = v > 0.f ? v : __expf(v) - 1.f;       // ELU
          Out[(size_t)(rr + j) * N + cc] = f2bf(v);
        }
      } else {
        float ps = 0.f, pd = 0.f;
#pragma unroll
        for (int n = 0; n < 4; ++n) {
          int cc = col0 + nBase + n * 16 + lane15;
          float v = acc[m][n][j];
          Out[(size_t)(rr + j) * N + cc] = f2bf(v);
          ps = fmaf(v, asv[n], ps);
          pd = fmaf(v, adv[n], pd);
        }
        ps += __shfl_xor(ps, 1); pd += __shfl_xor(pd, 1);
        ps += __shfl_xor(ps, 2); pd += __shfl_xor(pd, 2);
        ps += __shfl_xor(ps, 4); pd += __shfl_xor(pd, 4);
        ps += __shfl_xor(ps, 8); pd += __shfl_xor(pd, 8);
        if (lane15 == 0) {                          // exactly one writer per slot
          asrcP[(size_t)(rr + j) * 16 + head * 4 + q] = ps;
          adstP[(size_t)(rr + j) * 16 + head * 4 + q] = pd;
        }
      }
    }
  }
}

// ---------------- repack h2 bf16->fp8 ∥ reduce alpha quarters -----------------------
__global__ void k_repack8(const unsigned short* __restrict__ hbf,
                          unsigned int* __restrict__ h8,
                          const float* __restrict__ asrcP,
                          const float* __restrict__ adstP,
                          float* __restrict__ asrcR,
                          float* __restrict__ adstR) {
  int b = blockIdx.x;
  if (b < 12288) {                                 // N*FDIM/4/256
    int i = b * 256 + threadIdx.x;                 // one output dword = 4 fp8
    ushort4 v = *reinterpret_cast<const ushort4*>(&hbf[(size_t)i * 4]);
    int w = __builtin_amdgcn_cvt_pk_fp8_f32(bf2f(v.x), bf2f(v.y), 0, false);
    w = __builtin_amdgcn_cvt_pk_fp8_f32(bf2f(v.z), bf2f(v.w), w, true);
    h8[i] = (unsigned int)w;
  } else {                                         // reduce quarters: N*4 scalars
    int i = (b - 12288) * 256 + threadIdx.x;
    float4 sq = *reinterpret_cast<const float4*>(&asrcP[(size_t)i * 4]);
    asrcR[i] = sq.x + sq.y + sq.z + sq.w;
    float4 dq = *reinterpret_cast<const float4*>(&adstP[(size_t)i * 4]);
    adstR[i] = dq.x + dq.y + dq.z + dq.w;
  }
}

// ---------------- GAT aggregation of fp8 h2: wave/node, TWO edges/iter ---------------
// 32 lanes × 32 features (8 fp8-dwords); halves process alternate edges; shfl merge.
__global__ __launch_bounds__(256) void k_agg4(const unsigned int* __restrict__ h8,
                                              const float* __restrict__ asrcR,
                                              const float* __restrict__ adstR,
                                              const int* __restrict__ row_ptr,
                                              const int* __restrict__ csr_src, const float* __restrict__ bias,
                                              unsigned short* __restrict__ outHi) {
  int node = (blockIdx.x * 256 + threadIdx.x) >> 6;
  int lane = threadIdx.x & 63;
  int half = lane >> 5, l = lane & 31;
  int hd = l >> 3;                                 // lane's 32 feats = [32l, 32l+32)
  int beg = row_ptr[node], end = row_ptr[node + 1];
  float adn = adstR[node * 4 + hd];
  float m = -INFINITY, s = 0.f;
  float acc[32];
#pragma unroll
  for (int k = 0; k < 32; ++k) acc[k] = 0.f;
  for (int e = beg + half; e < end; e += 2) {
    int sidx = csr_src[e];
    float a = asrcR[sidx * 4 + hd] + adn;
    a = a > 0.f ? a : NEG_SLOPE * a;            // leaky_relu
    float nm = fmaxf(m, a);
    float sc = __expf(m - nm);
    float p  = __expf(a - nm);
    m = nm;
    s = s * sc + p;
    const unsigned int* rp = h8 + (size_t)sidx * 256 + l * 8;
    uint4 dw0 = *reinterpret_cast<const uint4*>(rp);
    uint4 dw1 = *reinterpret_cast<const uint4*>(rp + 4);
#pragma unroll
    for (int d = 0; d < 4; ++d) {
      unsigned int w = (&dw0.x)[d];
      f32x2 lo = __builtin_amdgcn_cvt_pk_f32_fp8(w, false);
      f32x2 hi = __builtin_amdgcn_cvt_pk_f32_fp8(w, true);
      acc[d * 4 + 0] = acc[d * 4 + 0] * sc + p * lo.x;
      acc[d * 4 + 1] = acc[d * 4 + 1] * sc + p * lo.y;
      acc[d * 4 + 2] = acc[d * 4 + 2] * sc + p * hi.x;
      acc[d * 4 + 3] = acc[d * 4 + 3] * sc + p * hi.y;
    }
#pragma unroll
    for (int d = 0; d < 4; ++d) {
      unsigned int w = (&dw1.x)[d];
      f32x2 lo = __builtin_amdgcn_cvt_pk_f32_fp8(w, false);
      f32x2 hi = __builtin_amdgcn_cvt_pk_f32_fp8(w, true);
      acc[16 + d * 4 + 0] = acc[16 + d * 4 + 0] * sc + p * lo.x;
      acc[16 + d * 4 + 1] = acc[16 + d * 4 + 1] * sc + p * lo.y;
      acc[16 + d * 4 + 2] = acc[16 + d * 4 + 2] * sc + p * hi.x;
      acc[16 + d * 4 + 3] = acc[16 + d * 4 + 3] * sc + p * hi.y;
    }
  }
  // merge half-wave states
  float mo = __shfl_xor(m, 32);
  float so = __shfl_xor(s, 32);
  float nm = fmaxf(m, mo);
  float scS = __expf(m - nm);
  float scO = __expf(mo - nm);
  s = s * scS + so * scO;
#pragma unroll
  for (int k = 0; k < 32; ++k) {
    float ao = __shfl_xor(acc[k], 32);
    acc[k] = acc[k] * scS + ao * scO;
  }
  if (half == 0) {
    float inv = 1.f / s;
    int fo = l * 32;
#pragma unroll
    for (int d = 0; d < 8; ++d) {
      float4 bv = *reinterpret_cast<const float4*>(&bias[fo + d * 4]);
      float v0 = acc[d * 4 + 0] * inv + bv.x;
      float v1 = acc[d * 4 + 1] * inv + bv.y;
      float v2 = acc[d * 4 + 2] * inv + bv.z;
      float v3 = acc[d * 4 + 3] * inv + bv.w;
      v0 = v0 > 0.f ? v0 : __expf(v0) - 1.f;       // ELU
      v1 = v1 > 0.f ? v1 : __expf(v1) - 1.f;
      v2 = v2 > 0.f ? v2 : __expf(v2) - 1.f;
      v3 = v3 > 0.f ? v3 : __expf(v3) - 1.f;
      ushort4 st;
      st.x = f2bf(v0); st.y = f2bf(v1); st.z = f2bf(v2); st.w = f2bf(v3);
      *reinterpret_cast<ushort4*>(&outHi[(size_t)node * FDIM + fo + d * 4]) = st;
    }
  }
}

// ---------------- layer-3 MFMA GEMM: [N,1024](bf16) @ w3t[16,1024]^T + alpha3 --------
__global__ __launch_bounds__(256) void k_gemm_n16(const unsigned short* __restrict__ A,
                                                  const unsigned short* __restrict__ w3t,
                                                  const float* __restrict__ a_s,
                                                  const float* __restrict__ a_d,
                                                  float* __restrict__ C,
                                                  float* __restrict__ asrc,
                                                  float* __restrict__ adst) {
  int wave = (blockIdx.x * 256 + threadIdx.x) >> 6;   // 0..767
  int lane = threadIdx.x & 63;
  int lane15 = lane & 15;
  int row0 = wave * 16;
  int kg = (lane >> 4) * 8;
  f32x4 acc = (f32x4){0.f, 0.f, 0.f, 0.f};
  const unsigned short* Ar = A + (size_t)(row0 + lane15) * FDIM + kg;
  const unsigned short* Br = w3t + (size_t)lane15 * FDIM + kg;
  for (int k0 = 0; k0 < FDIM; k0 += 32) {
    short8 a = *reinterpret_cast<const short8*>(Ar + k0);
    short8 b = *reinterpret_cast<const short8*>(Br + k0);
    acc = __builtin_amdgcn_mfma_f32_16x16x32_bf16(a, b, acc, 0, 0, 0);
  }
  float asv = a_s[lane15], adv = a_d[lane15];
  int rbase = row0 + (lane >> 4) * 4;
#pragma unroll
  for (int j = 0; j < 4; ++j) {
    float v = acc[j];
    C[(size_t)(rbase + j) * EMB + lane15] = v;
    float ps = v * asv, pd = v * adv;
    ps += __shfl_xor(ps, 1); pd += __shfl_xor(pd, 1);
    ps += __shfl_xor(ps, 2); pd += __shfl_xor(pd, 2);
    ps += __shfl_xor(ps, 4); pd += __shfl_xor(pd, 4);
    ps += __shfl_xor(ps, 8); pd += __shfl_xor(pd, 8);
    if (lane15 == 0) { asrc[rbase + j] = ps; adst[rbase + j] = pd; }
  }
}

// layer-3 aggregation (16 threads/node, online) + fused q + z hi/lo bf16 -------------
__global__ __launch_bounds__(256) void k_agg1(const float* __restrict__ h3, const float* __restrict__ asrc,
                                              const float* __restrict__ adst, const int* __restrict__ row_ptr,
                                              const int* __restrict__ csr_src, const float* __restrict__ bias,
                                              const float* __restrict__ centers,
                                              float* __restrict__ z, float* __restrict__ qout,
                                              unsigned short* __restrict__ zh,
                                              unsigned short* __restrict__ zl) {
  int idx = blockIdx.x * 256 + threadIdx.x;
  int node = idx >> 4, f = idx & 15;
  if (node >= N_NODES) return;
  int beg = row_ptr[node], end = row_ptr[node + 1];
  float adn = adst[node];
  float m = -INFINITY, s = 0.f, acc = 0.f;
  for (int e = beg; e < end; ++e) {
    int sidx = csr_src[e];
    float a = asrc[sidx] + adn;
    a = a > 0.f ? a : NEG_SLOPE * a;
    float nm = fmaxf(m, a);
    float sc = __expf(m - nm);
    float p  = __expf(a - nm);
    m = nm;
    s = s * sc + p;
    acc = acc * sc + p * h3[sidx * EMB + f];
  }
  float zv = acc / s + bias[f];
  z[node * EMB + f] = zv;
  unsigned short hv = f2bf(zv);
  zh[node * EMB + f] = hv;
  zl[node * EMB + f] = f2bf(zv - bf2f(hv));
  float d0 = zv - centers[f];       d0 *= d0;
  float d1 = zv - centers[EMB + f]; d1 *= d1;
  d0 += __shfl_xor(d0, 1); d1 += __shfl_xor(d1, 1);
  d0 += __shfl_xor(d0, 2); d1 += __shfl_xor(d1, 2);
  d0 += __shfl_xor(d0, 4); d1 += __shfl_xor(d1, 4);
  d0 += __shfl_xor(d0, 8); d1 += __shfl_xor(d1, 8);
  if (f == 0) {
    float q0 = 1.f / (1.f + d0), q1 = 1.f / (1.f + d1);
    float inv = 1.f / (q0 + q1);
    qout[node * 2 + 0] = q0 * inv;
    qout[node * 2 + 1] = q1 * inv;
  }
}

// ---------------- adjacency: sigmoid(z @ z^T) via MFMA, hi/lo 3-term -----------------
__global__ __launch_bounds__(256) void k_adj(const unsigned short* __restrict__ zh,
                                             const unsigned short* __restrict__ zl,
                                             float* __restrict__ adj) {
  int tid = threadIdx.x;
  int lane = tid & 63, wv = tid >> 6;
  int r0 = blockIdx.y * 128 + wv * 32, c0 = blockIdx.x * 128;
  int l15 = lane & 15, kg = lane >> 4;
  short8 zero = (short8){0, 0, 0, 0, 0, 0, 0, 0};
  short8 ah[2], al[2];
#pragma unroll
  for (int g = 0; g < 2; ++g) {
    int row = r0 + g * 16 + l15;
    if (kg < 2) {
      ah[g] = *reinterpret_cast<const short8*>(&zh[(size_t)row * EMB + kg * 8]);
      al[g] = *reinterpret_cast<const short8*>(&zl[(size_t)row * EMB + kg * 8]);
    } else { ah[g] = zero; al[g] = zero; }
  }
  short8 bh[8], bl[8];
#pragma unroll
  for (int n = 0; n < 8; ++n) {
    int col = c0 + n * 16 + l15;
    if (kg < 2) {
      bh[n] = *reinterpret_cast<const short8*>(&zh[(size_t)col * EMB + kg * 8]);
      bl[n] = *reinterpret_cast<const short8*>(&zl[(size_t)col * EMB + kg * 8]);
    } else { bh[n] = zero; bl[n] = zero; }
  }
#pragma unroll
  for (int g = 0; g < 2; ++g) {
    int rbase = r0 + g * 16 + kg * 4;
#pragma unroll
    for (int n = 0; n < 8; ++n) {
      f32x4 acc = (f32x4){0.f, 0.f, 0.f, 0.f};
      acc = __builtin_amdgcn_mfma_f32_16x16x32_bf16(ah[g], bh[n], acc, 0, 0, 0);
      acc = __builtin_amdgcn_mfma_f32_16x16x32_bf16(ah[g], bl[n], acc, 0, 0, 0);
      acc = __builtin_amdgcn_mfma_f32_16x16x32_bf16(al[g], bh[n], acc, 0, 0, 0);
      int cc = c0 + n * 16 + l15;
#pragma unroll
      for (int j = 0; j < 4; ++j) {
        float v = 1.f / (1.f + __expf(-acc[j]));
        adj[(size_t)(rbase + j) * N_NODES + cc] = v;
      }
    }
  }
}

// ====================================================================================
extern "C" void kernel_launch(void* const* d_in, const int* in_sizes, int n_in,
                              void* d_out, int out_size, void* d_ws, size_t ws_size,
                              hipStream_t stream) {
  const float* x   = (const float*)d_in[0];
  const int*   ei  = (const int*)d_in[1];
  const float* W1  = (const float*)d_in[2];
  const float* as1 = (const float*)d_in[3];
  const float* ad1 = (const float*)d_in[4];
  const float* b1  = (const float*)d_in[5];
  const float* W2  = (const float*)d_in[6];
  const float* as2 = (const float*)d_in[7];
  const float* ad2 = (const float*)d_in[8];
  const float* b2  = (const float*)d_in[9];
  const float* W3  = (const float*)d_in[10];
  const float* as3 = (const float*)d_in[11];
  const float* ad3 = (const float*)d_in[12];
  const float* b3  = (const float*)d_in[13];
  const float* centers = (const float*)d_in[14];
  float* out = (float*)d_out;

  char* ws = (char*)d_ws;
  size_t off = 0;
  auto alloc = [&](size_t bytes) { void* p = ws + off; off = (off + bytes + 255) & ~(size_t)255; return p; };
  int* cnt       = (int*)alloc((size_t)N_NODES * 4);           // cnt+cur contiguous
  int* cur       = (int*)alloc((size_t)N_NODES * 4);
  int* row_ptr   = (int*)alloc((size_t)(N_NODES + 1) * 4);
  int* bsum      = (int*)alloc(64 * 4);
  int* csr_src   = (int*)alloc((size_t)EP_EDGES * 4);
  float* asrcA   = (float*)alloc((size_t)N_NODES * HEADS * 4);
  float* adstA   = (float*)alloc((size_t)N_NODES * HEADS * 4);
  float* asrcP   = (float*)alloc((size_t)N_NODES * 16 * 4);    // per-(row,head,quarter)
  float* adstP   = (float*)alloc((size_t)N_NODES * 16 * 4);
  float* asrcR   = (float*)alloc((size_t)N_NODES * 4 * 4);     // reduced per-(node,head)
  float* adstR   = (float*)alloc((size_t)N_NODES * 4 * 4);
  float* asrc3   = (float*)alloc((size_t)N_NODES * 4);
  float* adst3   = (float*)alloc((size_t)N_NODES * 4);
  float* wa      = (float*)alloc(1024 * 4);
  unsigned int*   x8     = (unsigned int*)alloc((size_t)N_NODES * 128);         // x fp8
  unsigned short* aggxHi = (unsigned short*)alloc((size_t)N_NODES * 512 * 2);
  unsigned short* h1bf   = (unsigned short*)alloc((size_t)N_NODES * FDIM * 2);
  unsigned short* hbf    = (unsigned short*)alloc((size_t)N_NODES * FDIM * 2);  // h2 bf16
  unsigned int*   h8     = (unsigned int*)alloc((size_t)N_NODES * FDIM);        // h2 fp8
  unsigned short* agg2Hi = (unsigned short*)alloc((size_t)N_NODES * FDIM * 2);
  unsigned short* w1tHi  = (unsigned short*)alloc((size_t)FDIM * 128 * 2);
  unsigned short* w2tHi  = (unsigned short*)alloc((size_t)FDIM * FDIM * 2);
  unsigned short* w3t    = (unsigned short*)alloc((size_t)16 * FDIM * 2);
  unsigned short* zh     = (unsigned short*)alloc((size_t)N_NODES * EMB * 2);
  unsigned short* zl     = (unsigned short*)alloc((size_t)N_NODES * EMB * 2);
  float* bufZ    = (float*)alloc((size_t)N_NODES * EMB * 4);

  hipMemsetAsync(cnt, 0, (size_t)N_NODES * 8, stream);                 // cnt + cur

  // ---- K1: hist ∥ prep (x->fp8, W1t, W2t, wa, W3t)
  k_hist_prep<<<dim3(HIST_BLKS + 1536 + 128 + 1024 + 2), dim3(256), 0, stream>>>(
      ei, cnt, x, x8, W1, w1tHi, W2, w2tHi, as1, ad1, wa, W3, w3t);

  // ---- K2: scan1 ∥ alpha_x
  k_scan_alpha<<<dim3(12 + 48), dim3(1024), 0, stream>>>(
      cnt, row_ptr, bsum, x, wa, asrcA, adstA);

  // ---- K3/K4: finish scan, scatter
  k_scan23<<<dim3(N_NODES / 256), dim3(256), 0, stream>>>(row_ptr, bsum);
  k_scatter<<<dim3((EP_EDGES + 255) / 256), dim3(256), 0, stream>>>(ei, row_ptr, cur, csr_src);

  // ---- layer 1 (commuted): aggregate x (2 edges/iter), project (+bias+ELU)
  k_aggx<<<dim3(N_NODES / 4), dim3(256), 0, stream>>>(x8, asrcA, adstA, row_ptr, csr_src, aggxHi);
  k_gemm<1><<<dim3(FDIM / 128, N_NODES / 128), dim3(256), 0, stream>>>(
      aggxHi, w1tHi, h1bf, b1, nullptr, nullptr, nullptr, nullptr, N_NODES, FDIM, 128, 512);

  // ---- layer 2: bf16 GEMM + fused alpha partials; repack->fp8 ∥ reduce alphas
  k_gemm<0><<<dim3(FDIM / 128, N_NODES / 128), dim3(256), 0, stream>>>(
      h1bf, w2tHi, hbf, nullptr, as2, ad2, asrcP, adstP, N_NODES, FDIM, FDIM, FDIM);
  k_repack8<<<dim3(12288 + N_NODES * 4 / 256), dim3(256), 0, stream>>>(
      hbf, h8, asrcP, adstP, asrcR, adstR);
  k_agg4<<<dim3(N_NODES / 4), dim3(256), 0, stream>>>(h8, asrcR, adstR, row_ptr, csr_src, b2, agg2Hi);

  // ---- layer 3: MFMA GEMM (alpha fused); agg1 fuses q + z hi/lo
  k_gemm_n16<<<dim3(N_NODES / 64), dim3(256), 0, stream>>>(
      agg2Hi, w3t, as3, ad3, bufZ, asrc3, adst3);
  float* adj = out + (size_t)N_NODES * EMB;
  float* q   = adj + (size_t)N_NODES * N_NODES;
  k_agg1<<<dim3(N_NODES * EMB / 256), dim3(256), 0, stream>>>(
      bufZ, asrc3, adst3, row_ptr, csr_src, b3, centers, out, q, zh, zl);

  // ---- adjacency decoder: MFMA z@z^T
  k_adj<<<dim3(N_NODES / 128, N_NODES / 128), dim3(256), 0, stream>>>(zh, zl, adj);
}